// Round 1
// baseline (480.166 us; speedup 1.0000x reference)
//
#include <hip/hip_runtime.h>
#include <cstdint>
#include <cstddef>

// Fused causal self-attention, MI355X gfx950.
// B=1, S=4096, D=1024, H=16, HD=64.
// Pipeline: [GEMM1: x@W_qkv+b -> Q,K,V^T bf16 in ws] -> [flash attn -> O bf16]
//           -> [GEMM2: O@W_out+b_out -> f32 d_out]
// ws usage: 4 * 16*4096*64 shorts * ... = 32 MB total.

typedef __attribute__((ext_vector_type(4))) float f32x4;
typedef __attribute__((ext_vector_type(8))) short s16x8;

#define LOG2E 1.4426950408889634f

static __device__ __forceinline__ short f2bf(float f) {
  unsigned u = __builtin_bit_cast(unsigned, f);
  u = (u + 0x7fffu + ((u >> 16) & 1u)) >> 16;   // round-to-nearest-even
  return (short)u;
}

// ---------------------------------------------------------------------------
// GEMM: C[M,N] = A[M,K] @ B[K,N] + bias, bf16 MFMA 16x16x32, f32 accum.
// 128x128 tile, BK=32, 256 threads (4 waves, 2x2), each wave 64x64 out.
// MODE 0: A = f32 (x), epilogue scatters bf16 into Q / K / V^T ws arrays.
// MODE 1: A = bf16 (o_ws), epilogue writes f32 out + bias.
// ---------------------------------------------------------------------------
template <int MODE>
__global__ __launch_bounds__(256, 2) void gemm_k(
    const void* __restrict__ Ap, const float* __restrict__ B,
    const float* __restrict__ bias,
    short* __restrict__ q_ws, short* __restrict__ k_ws, short* __restrict__ vt_ws,
    float* __restrict__ out, int M, int N, int K) {
  __shared__ short As[128][40];   // [m][k], +8 pad breaks bank conflicts
  __shared__ short Bs[128][40];   // [n][k] (transposed so frag reads are k-contiguous)

  const int t  = threadIdx.x;
  const int l  = t & 63;
  const int w  = t >> 6;
  const int wm = (w >> 1) * 64, wn = (w & 1) * 64;
  const int m0 = blockIdx.x * 128, n0 = blockIdx.y * 128;
  const int lr = l & 15, lh = l >> 4;

  f32x4 acc[4][4];
#pragma unroll
  for (int i = 0; i < 4; i++)
#pragma unroll
    for (int j = 0; j < 4; j++) acc[i][j] = (f32x4){0.f, 0.f, 0.f, 0.f};

  const int arow = t >> 1, ac0 = (t & 1) * 16;   // A tile: 128 rows x 32 k
  const int bk = t >> 3, bc0 = (t & 7) * 16;     // B tile: 32 k-rows x 128 n

  for (int kt = 0; kt < K; kt += 32) {
    // ---- stage A tile (convert f32->bf16 for MODE 0) ----
    if constexpr (MODE == 0) {
      const float* ap = (const float*)Ap + (size_t)(m0 + arow) * K + kt + ac0;
      float4 v0 = *(const float4*)(ap + 0);
      float4 v1 = *(const float4*)(ap + 4);
      float4 v2 = *(const float4*)(ap + 8);
      float4 v3 = *(const float4*)(ap + 12);
      s16x8 o0, o1;
      o0[0] = f2bf(v0.x); o0[1] = f2bf(v0.y); o0[2] = f2bf(v0.z); o0[3] = f2bf(v0.w);
      o0[4] = f2bf(v1.x); o0[5] = f2bf(v1.y); o0[6] = f2bf(v1.z); o0[7] = f2bf(v1.w);
      o1[0] = f2bf(v2.x); o1[1] = f2bf(v2.y); o1[2] = f2bf(v2.z); o1[3] = f2bf(v2.w);
      o1[4] = f2bf(v3.x); o1[5] = f2bf(v3.y); o1[6] = f2bf(v3.z); o1[7] = f2bf(v3.w);
      *(s16x8*)&As[arow][ac0]     = o0;
      *(s16x8*)&As[arow][ac0 + 8] = o1;
    } else {
      const short* ap = (const short*)Ap + (size_t)(m0 + arow) * K + kt + ac0;
      *(s16x8*)&As[arow][ac0]     = *(const s16x8*)ap;
      *(s16x8*)&As[arow][ac0 + 8] = *(const s16x8*)(ap + 8);
    }
    // ---- stage B tile transposed ----
    {
      const float* bp = B + (size_t)(kt + bk) * N + n0 + bc0;
      float4 v0 = *(const float4*)(bp + 0);
      float4 v1 = *(const float4*)(bp + 4);
      float4 v2 = *(const float4*)(bp + 8);
      float4 v3 = *(const float4*)(bp + 12);
      short tb[16];
      tb[0]  = f2bf(v0.x); tb[1]  = f2bf(v0.y); tb[2]  = f2bf(v0.z); tb[3]  = f2bf(v0.w);
      tb[4]  = f2bf(v1.x); tb[5]  = f2bf(v1.y); tb[6]  = f2bf(v1.z); tb[7]  = f2bf(v1.w);
      tb[8]  = f2bf(v2.x); tb[9]  = f2bf(v2.y); tb[10] = f2bf(v2.z); tb[11] = f2bf(v2.w);
      tb[12] = f2bf(v3.x); tb[13] = f2bf(v3.y); tb[14] = f2bf(v3.z); tb[15] = f2bf(v3.w);
#pragma unroll
      for (int i = 0; i < 16; i++) Bs[bc0 + i][bk] = tb[i];
    }
    __syncthreads();

    // ---- compute: 16 MFMA per wave per K-step ----
    s16x8 af[4], bfv[4];
#pragma unroll
    for (int mi = 0; mi < 4; mi++)
      af[mi] = *(const s16x8*)&As[wm + mi * 16 + lr][lh * 8];
#pragma unroll
    for (int ni = 0; ni < 4; ni++)
      bfv[ni] = *(const s16x8*)&Bs[wn + ni * 16 + lr][lh * 8];
#pragma unroll
    for (int mi = 0; mi < 4; mi++)
#pragma unroll
      for (int ni = 0; ni < 4; ni++)
        acc[mi][ni] = __builtin_amdgcn_mfma_f32_16x16x32_bf16(af[mi], bfv[ni],
                                                              acc[mi][ni], 0, 0, 0);
    __syncthreads();
  }

  // ---- epilogue ----
#pragma unroll
  for (int mi = 0; mi < 4; mi++) {
#pragma unroll
    for (int ni = 0; ni < 4; ni++) {
      const int gn = n0 + wn + ni * 16 + lr;
      const float bb = bias[gn];
      if constexpr (MODE == 0) {
        const int sect = gn >> 10, dd = gn & 1023, hh = dd >> 6, hd = dd & 63;
#pragma unroll
        for (int j = 0; j < 4; j++) {
          const int gm = m0 + wm + mi * 16 + lh * 4 + j;   // token index s
          const short bv = f2bf(acc[mi][ni][j] + bb);
          if (sect == 0)      q_ws[((size_t)hh * 4096 + gm) * 64 + hd] = bv;
          else if (sect == 1) k_ws[((size_t)hh * 4096 + gm) * 64 + hd] = bv;
          else                vt_ws[((size_t)hh * 64 + hd) * 4096 + gm] = bv;
        }
      } else {
#pragma unroll
        for (int j = 0; j < 4; j++) {
          const int gm = m0 + wm + mi * 16 + lh * 4 + j;
          out[(size_t)gm * N + gn] = acc[mi][ni][j] + bb;
        }
      }
    }
  }
}

// ---------------------------------------------------------------------------
// Flash-style causal attention. One block = (head, 64 q-rows), 4 waves,
// each wave owns 16 q-rows x full HD=64. KV tiles of 64, staged in LDS.
// ---------------------------------------------------------------------------
__global__ __launch_bounds__(256, 2) void attn_k(
    const short* __restrict__ q_ws, const short* __restrict__ k_ws,
    const short* __restrict__ vt_ws, short* __restrict__ o_ws) {
  __shared__ short Ks[64][72];    // [kv][hd], +8 pad
  __shared__ short Vts[64][72];   // [hd][kv], +8 pad
  __shared__ short Ps[64][72];    // [q(4 waves x 16)][kv], +8 pad

  const int t = threadIdx.x, l = t & 63, w = t >> 6;
  const int lr = l & 15, lh = l >> 4;
  const int h = blockIdx.y;
  const int qb = blockIdx.x * 64;
  const int qrow_w = qb + w * 16;

  // Q fragments (A-operand): lane holds Q[qrow_w + lr][kk*32 + lh*8 + j]
  s16x8 qf[2];
  {
    const short* qp = q_ws + ((size_t)h * 4096 + qrow_w + lr) * 64 + lh * 8;
    qf[0] = *(const s16x8*)qp;
    qf[1] = *(const s16x8*)(qp + 32);
  }

  f32x4 po[4];
#pragma unroll
  for (int n = 0; n < 4; n++) po[n] = (f32x4){0.f, 0.f, 0.f, 0.f};
  float mj[4], lj[4];
#pragma unroll
  for (int j = 0; j < 4; j++) { mj[j] = -1e30f; lj[j] = 0.f; }

  const int srow = t >> 2, sc0 = (t & 3) * 16;   // staging: 64 rows x 64 cols
  const int nkv = qb / 64 + 1;

  for (int kt = 0; kt < nkv; kt++) {
    const int kv0 = kt * 64;
    __syncthreads();
    {
      const short* kp = k_ws + ((size_t)h * 4096 + kv0 + srow) * 64 + sc0;
      *(s16x8*)&Ks[srow][sc0]     = *(const s16x8*)kp;
      *(s16x8*)&Ks[srow][sc0 + 8] = *(const s16x8*)(kp + 8);
      const short* vp = vt_ws + ((size_t)h * 64 + srow) * 4096 + kv0 + sc0;
      *(s16x8*)&Vts[srow][sc0]     = *(const s16x8*)vp;
      *(s16x8*)&Vts[srow][sc0 + 8] = *(const s16x8*)(vp + 8);
    }
    __syncthreads();

    // S = Q K^T : sa[tt][j] = S[q = qrow_w + lh*4 + j][kv = kv0 + tt*16 + lr]
    f32x4 sa[4];
#pragma unroll
    for (int tt = 0; tt < 4; tt++) {
      sa[tt] = (f32x4){0.f, 0.f, 0.f, 0.f};
#pragma unroll
      for (int kk = 0; kk < 2; kk++) {
        s16x8 kf = *(const s16x8*)&Ks[tt * 16 + lr][kk * 32 + lh * 8];
        sa[tt] = __builtin_amdgcn_mfma_f32_16x16x32_bf16(qf[kk], kf, sa[tt], 0, 0, 0);
      }
    }

    const bool diag = (kt == nkv - 1);
#pragma unroll
    for (int j = 0; j < 4; j++) {
      const int qi = qrow_w + lh * 4 + j;
      float pm = -1e30f;
#pragma unroll
      for (int tt = 0; tt < 4; tt++) {
        float v = sa[tt][j] * 0.125f;   // 1/sqrt(64)
        if (diag && (kv0 + tt * 16 + lr > qi)) v = -1e30f;
        sa[tt][j] = v;
        pm = fmaxf(pm, v);
      }
      // row-reduce across the 16 lanes holding this row (xor 1,2,4,8)
      pm = fmaxf(pm, __shfl_xor(pm, 1));
      pm = fmaxf(pm, __shfl_xor(pm, 2));
      pm = fmaxf(pm, __shfl_xor(pm, 4));
      pm = fmaxf(pm, __shfl_xor(pm, 8));
      const float nm = fmaxf(mj[j], pm);
      const float corr = exp2f((mj[j] - nm) * LOG2E);
      mj[j] = nm;
      float rs = 0.f;
#pragma unroll
      for (int tt = 0; tt < 4; tt++) {
        float p = exp2f((sa[tt][j] - nm) * LOG2E);
        sa[tt][j] = p;
        rs += p;
      }
      rs += __shfl_xor(rs, 1);
      rs += __shfl_xor(rs, 2);
      rs += __shfl_xor(rs, 4);
      rs += __shfl_xor(rs, 8);
      lj[j] = lj[j] * corr + rs;
#pragma unroll
      for (int n = 0; n < 4; n++) po[n][j] *= corr;
    }

    // P (C-layout) -> LDS -> A-layout fragments for PV (per-wave region)
#pragma unroll
    for (int tt = 0; tt < 4; tt++)
#pragma unroll
      for (int j = 0; j < 4; j++)
        Ps[w * 16 + lh * 4 + j][tt * 16 + lr] = f2bf(sa[tt][j]);
    asm volatile("s_waitcnt lgkmcnt(0)" ::: "memory");

    s16x8 pf[2];
#pragma unroll
    for (int kk = 0; kk < 2; kk++)
      pf[kk] = *(const s16x8*)&Ps[w * 16 + lr][kk * 32 + lh * 8];
#pragma unroll
    for (int n = 0; n < 4; n++) {
#pragma unroll
      for (int kk = 0; kk < 2; kk++) {
        s16x8 vf = *(const s16x8*)&Vts[n * 16 + lr][kk * 32 + lh * 8];
        po[n] = __builtin_amdgcn_mfma_f32_16x16x32_bf16(pf[kk], vf, po[n], 0, 0, 0);
      }
    }
  }

  // O = po / l, write bf16 [S][D] at col h*64+hd
#pragma unroll
  for (int n = 0; n < 4; n++) {
#pragma unroll
    for (int j = 0; j < 4; j++) {
      const float o = po[n][j] / lj[j];
      o_ws[((size_t)qb + w * 16 + lh * 4 + j) * 1024 + h * 64 + n * 16 + lr] = f2bf(o);
    }
  }
}

// ---------------------------------------------------------------------------
extern "C" void kernel_launch(void* const* d_in, const int* in_sizes, int n_in,
                              void* d_out, int out_size, void* d_ws, size_t ws_size,
                              hipStream_t stream) {
  const float* x     = (const float*)d_in[0];
  const float* W_qkv = (const float*)d_in[1];
  const float* b_qkv = (const float*)d_in[2];
  const float* W_out = (const float*)d_in[3];
  const float* b_out = (const float*)d_in[4];
  float* out = (float*)d_out;

  const size_t HSZ = (size_t)16 * 4096 * 64;   // 4M elems per Q/K/V^T array
  short* q_ws  = (short*)d_ws;
  short* k_ws  = q_ws + HSZ;
  short* vt_ws = k_ws + HSZ;
  short* o_ws  = vt_ws + HSZ;                   // [4096][1024] bf16

  // x @ W_qkv + b_qkv -> Q [H][S][64], K [H][S][64], V^T [H][64][S] (bf16)
  gemm_k<0><<<dim3(32, 24), 256, 0, stream>>>(
      x, W_qkv, b_qkv, q_ws, k_ws, vt_ws, nullptr, 4096, 3072, 1024);
  // causal flash attention -> O [S][D] bf16
  attn_k<<<dim3(64, 16), 256, 0, stream>>>(q_ws, k_ws, vt_ws, o_ws);
  // O @ W_out + b_out -> f32
  gemm_k<1><<<dim3(32, 8), 256, 0, stream>>>(
      o_ws, W_out, b_out, nullptr, nullptr, nullptr, out, 4096, 1024, 1024);
}

// Round 2
// 305.040 us; speedup vs baseline: 1.5741x; 1.5741x over previous
//
#include <hip/hip_runtime.h>
#include <cstdint>
#include <cstddef>

// Fused causal self-attention, MI355X gfx950. B=1,S=4096,D=1024,H=16,HD=64.
// ws layout (shorts), 32MB total:
//   R0 @0      : Wqkv_t [3072][1024] bf16 (6MB), later overlaid by O [4096][1024] bf16 (8MB)
//   q  @4M     : Q  [16][4096][64] bf16
//   k  @8M     : K  [16][4096][64] bf16, hd-swizzled: pos = hd ^ ((s&7)<<3)
//   vt @12M    : V^T[16][64][4096] bf16, s-swizzled:  pos = s  ^ ((hd&7)<<3)
//                later overlaid by Wo_t [1024][1024] bf16 (2MB, after attn)
// Pipeline: convT(Wqkv) -> gemm<0> -> attn -> convT(Wout) -> gemm<1>

typedef __attribute__((ext_vector_type(4))) float f32x4;
typedef __attribute__((ext_vector_type(8))) short s16x8;

#define SM_SCALE_LOG2 0.18033688011112042f  // (1/sqrt(64)) * log2(e)

static __device__ __forceinline__ short f2bf(float f) {
  unsigned u = __builtin_bit_cast(unsigned, f);
  u = (u + 0x7fffu + ((u >> 16) & 1u)) >> 16;  // RNE
  return (short)u;
}

static __device__ __forceinline__ void gload16(const void* g, void* l) {
  __builtin_amdgcn_global_load_lds((const __attribute__((address_space(1))) void*)g,
                                   (__attribute__((address_space(3))) void*)l, 16, 0, 0);
}

// ---------------------------------------------------------------------------
// Convert + transpose: W[K][N] f32 -> Wt[N][K] bf16. 64x64 tiles.
// ---------------------------------------------------------------------------
__global__ __launch_bounds__(256, 2) void convT_k(const float* __restrict__ W,
                                                  short* __restrict__ Wt, int K, int N) {
  __shared__ short T[64][72];
  const int t = threadIdx.x;
  const int n0 = blockIdx.x * 64, k0 = blockIdx.y * 64;
  const int kr = t >> 2, c0 = (t & 3) * 16;
  const float* src = W + (size_t)(k0 + kr) * N + n0 + c0;
  float4 v0 = *(const float4*)(src + 0);
  float4 v1 = *(const float4*)(src + 4);
  float4 v2 = *(const float4*)(src + 8);
  float4 v3 = *(const float4*)(src + 12);
  T[c0 + 0][kr] = f2bf(v0.x);  T[c0 + 1][kr] = f2bf(v0.y);
  T[c0 + 2][kr] = f2bf(v0.z);  T[c0 + 3][kr] = f2bf(v0.w);
  T[c0 + 4][kr] = f2bf(v1.x);  T[c0 + 5][kr] = f2bf(v1.y);
  T[c0 + 6][kr] = f2bf(v1.z);  T[c0 + 7][kr] = f2bf(v1.w);
  T[c0 + 8][kr] = f2bf(v2.x);  T[c0 + 9][kr] = f2bf(v2.y);
  T[c0 + 10][kr] = f2bf(v2.z); T[c0 + 11][kr] = f2bf(v2.w);
  T[c0 + 12][kr] = f2bf(v3.x); T[c0 + 13][kr] = f2bf(v3.y);
  T[c0 + 14][kr] = f2bf(v3.z); T[c0 + 15][kr] = f2bf(v3.w);
  __syncthreads();
  const int nr = t >> 2, kc = (t & 3) * 16;
  s16x8 a = *(const s16x8*)&T[nr][kc];
  s16x8 b = *(const s16x8*)&T[nr][kc + 8];
  short* dst = Wt + (size_t)(n0 + nr) * K + k0 + kc;
  *(s16x8*)dst = a;
  *(s16x8*)(dst + 8) = b;
}

// ---------------------------------------------------------------------------
// GEMM C[M,N] = A[M,K] @ Bt[N,K]^T + bias. 128x128 tile, BK=32, 4 waves 2x2,
// double-buffered LDS, B (and A in MODE 1) staged via global_load_lds.
// MODE 0: A=f32 x (reg-staged cvt), scatter epilogue -> q/k(swz)/vt(swz).
// MODE 1: A=bf16 (gload_lds), f32 out + bias.
// ---------------------------------------------------------------------------
template <int MODE>
__global__ __launch_bounds__(256, 2) void gemm_k(
    const void* __restrict__ Ap, const short* __restrict__ Bt,
    const float* __restrict__ bias,
    short* __restrict__ q_ws, short* __restrict__ k_ws, short* __restrict__ vt_ws,
    float* __restrict__ out, int N, int K) {
  constexpr int LDA = (MODE == 0) ? 40 : 32;
  __shared__ short As[2][128 * LDA];
  __shared__ short Bs[2][128 * 32];

  const int t = threadIdx.x, l = t & 63, w = t >> 6;
  const int wm = (w >> 1) * 64, wn = (w & 1) * 64;
  const int m0 = blockIdx.x * 128, n0 = blockIdx.y * 128;
  const int lr = l & 15, lh = l >> 4;

  f32x4 acc[4][4];
#pragma unroll
  for (int i = 0; i < 4; i++)
#pragma unroll
    for (int j = 0; j < 4; j++) acc[i][j] = (f32x4){0.f, 0.f, 0.f, 0.f};

  const int arow = t >> 1, ac0 = (t & 1) * 16;  // MODE0 A staging map
  const int grow = l >> 2, gc0 = (l & 3) * 8;   // gload lane map: 16 rows / KB

  auto stage = [&](int b, int kt) {
    {  // B: 2 gload_lds per wave
      const int r0 = w * 32;
      const short* s0 = Bt + (size_t)(n0 + r0 + grow) * K + kt + gc0;
      gload16(s0, &Bs[b][r0 * 32]);
      gload16(s0 + (size_t)16 * K, &Bs[b][(r0 + 16) * 32]);
    }
    if constexpr (MODE == 0) {
      const float* ap = (const float*)Ap + (size_t)(m0 + arow) * K + kt + ac0;
      float4 v0 = *(const float4*)(ap + 0);
      float4 v1 = *(const float4*)(ap + 4);
      float4 v2 = *(const float4*)(ap + 8);
      float4 v3 = *(const float4*)(ap + 12);
      s16x8 o0, o1;
      o0[0] = f2bf(v0.x); o0[1] = f2bf(v0.y); o0[2] = f2bf(v0.z); o0[3] = f2bf(v0.w);
      o0[4] = f2bf(v1.x); o0[5] = f2bf(v1.y); o0[6] = f2bf(v1.z); o0[7] = f2bf(v1.w);
      o1[0] = f2bf(v2.x); o1[1] = f2bf(v2.y); o1[2] = f2bf(v2.z); o1[3] = f2bf(v2.w);
      o1[4] = f2bf(v3.x); o1[5] = f2bf(v3.y); o1[6] = f2bf(v3.z); o1[7] = f2bf(v3.w);
      *(s16x8*)&As[b][arow * LDA + ac0] = o0;
      *(s16x8*)&As[b][arow * LDA + ac0 + 8] = o1;
    } else {
      const int r0 = w * 32;
      const short* s0 = (const short*)Ap + (size_t)(m0 + r0 + grow) * K + kt + gc0;
      gload16(s0, &As[b][r0 * 32]);
      gload16(s0 + (size_t)16 * K, &As[b][(r0 + 16) * 32]);
    }
  };

  const int nt = K >> 5;
  stage(0, 0);
  __syncthreads();
  int cur = 0;
  for (int tt = 0; tt < nt; tt++) {
    if (tt + 1 < nt) stage(cur ^ 1, (tt + 1) * 32);
    s16x8 af[4], bfv[4];
#pragma unroll
    for (int mi = 0; mi < 4; mi++)
      af[mi] = *(const s16x8*)&As[cur][(wm + mi * 16 + lr) * LDA + lh * 8];
#pragma unroll
    for (int ni = 0; ni < 4; ni++)
      bfv[ni] = *(const s16x8*)&Bs[cur][(wn + ni * 16 + lr) * 32 + lh * 8];
#pragma unroll
    for (int mi = 0; mi < 4; mi++)
#pragma unroll
      for (int ni = 0; ni < 4; ni++)
        acc[mi][ni] = __builtin_amdgcn_mfma_f32_16x16x32_bf16(af[mi], bfv[ni],
                                                              acc[mi][ni], 0, 0, 0);
    __syncthreads();
    cur ^= 1;
  }

#pragma unroll
  for (int mi = 0; mi < 4; mi++) {
#pragma unroll
    for (int ni = 0; ni < 4; ni++) {
      const int gn = n0 + wn + ni * 16 + lr;
      const float bb = bias[gn];
      if constexpr (MODE == 0) {
        const int sect = gn >> 10, dd = gn & 1023, hh = dd >> 6, hd = dd & 63;
#pragma unroll
        for (int j = 0; j < 4; j++) {
          const int gm = m0 + wm + mi * 16 + lh * 4 + j;  // token s
          const short bv = f2bf(acc[mi][ni][j] + bb);
          if (sect == 0)
            q_ws[((size_t)hh * 4096 + gm) * 64 + hd] = bv;
          else if (sect == 1)
            k_ws[((size_t)hh * 4096 + gm) * 64 + (hd ^ ((gm & 7) << 3))] = bv;
          else
            vt_ws[((size_t)hh * 64 + hd) * 4096 + (gm ^ ((hd & 7) << 3))] = bv;
        }
      } else {
#pragma unroll
        for (int j = 0; j < 4; j++) {
          const int gm = m0 + wm + mi * 16 + lh * 4 + j;
          out[(size_t)gm * N + gn] = acc[mi][ni][j] + bb;
        }
      }
    }
  }
}

// ---------------------------------------------------------------------------
// Flash attention v2: swapped QK^T (S^T = K Q^T) so softmax is in-lane.
// Block = (head, 64 q-rows), 4 waves x 16 q-rows. KV tile 64, double-buffered,
// staged via global_load_lds from pre-swizzled K / V^T (conflict-free reads).
// ---------------------------------------------------------------------------
__global__ __launch_bounds__(256, 2) void attn_k(
    const short* __restrict__ q_ws, const short* __restrict__ k_ws,
    const short* __restrict__ vt_ws, short* __restrict__ o_ws) {
  __shared__ short Ks[2][64 * 64];   // [kv][hd], hd-swizzled storage
  __shared__ short Vts[2][64 * 64];  // [hd][kv], kv-swizzled storage
  __shared__ short Ps[4][16 * 72];   // per-wave P transpose buffer

  const int t = threadIdx.x, l = t & 63, w = t >> 6;
  const int lr = l & 15, lh = l >> 4;
  const int h = blockIdx.y;
  const int qbi = gridDim.x - 1 - blockIdx.x;  // biggest blocks first
  const int qb = qbi * 64;
  const int qrow_w = qb + w * 16;
  const int nkv = qbi + 1;

  // Q fragments (B-operand: lane holds Q[q=qrow_w+lr][kk*32+lh*8+j])
  s16x8 qf[2];
  {
    const short* qp = q_ws + ((size_t)h * 4096 + qrow_w + lr) * 64 + lh * 8;
    qf[0] = *(const s16x8*)qp;
    qf[1] = *(const s16x8*)(qp + 32);
  }

  f32x4 po[4];
#pragma unroll
  for (int n = 0; n < 4; n++) po[n] = (f32x4){0.f, 0.f, 0.f, 0.f};
  float m = -1e30f, lsum = 0.f;

  const int rowb = w * 16 + (l >> 3), c8 = (l & 7) * 8;  // staging lane map
  auto stage = [&](int b, int kv0) {
    const short* ks = k_ws + ((size_t)h * 4096 + kv0 + rowb) * 64 + c8;
    gload16(ks, &Ks[b][(w * 16) * 64]);
    gload16(ks + (size_t)8 * 64, &Ks[b][(w * 16 + 8) * 64]);
    const short* vs = vt_ws + ((size_t)h * 64 + rowb) * 4096 + kv0 + c8;
    gload16(vs, &Vts[b][(w * 16) * 64]);
    gload16(vs + (size_t)8 * 4096, &Vts[b][(w * 16 + 8) * 64]);
  };

  stage(0, 0);
  __syncthreads();
  int cur = 0;
  for (int kt = 0; kt < nkv; kt++) {
    const int kv0 = kt * 64;
    if (kt + 1 < nkv) stage(cur ^ 1, kv0 + 64);

    // S^T = K Q^T : sa[tt][j] = S[q=qrow_w+lr][kv=kv0+tt*16+lh*4+j]
    f32x4 sa[4];
#pragma unroll
    for (int tt = 0; tt < 4; tt++) {
      sa[tt] = (f32x4){0.f, 0.f, 0.f, 0.f};
#pragma unroll
      for (int kk = 0; kk < 2; kk++) {
        s16x8 kf = *(const s16x8*)&Ks[cur][(tt * 16 + lr) * 64 +
                                           ((kk * 32 + lh * 8) ^ ((lr & 7) << 3))];
        sa[tt] = __builtin_amdgcn_mfma_f32_16x16x32_bf16(kf, qf[kk], sa[tt], 0, 0, 0);
      }
    }

    const bool diag = (kt == nkv - 1);
    const int qi = qrow_w + lr;
    float smax = -3e38f;
#pragma unroll
    for (int tt = 0; tt < 4; tt++)
#pragma unroll
      for (int j = 0; j < 4; j++) {
        float v = sa[tt][j] * SM_SCALE_LOG2;
        if (diag && (kv0 + tt * 16 + lh * 4 + j > qi)) v = -3e38f;
        sa[tt][j] = v;
        smax = fmaxf(smax, v);
      }
    smax = fmaxf(smax, __shfl_xor(smax, 16));
    smax = fmaxf(smax, __shfl_xor(smax, 32));
    const float nm = fmaxf(m, smax);
    const float corr = exp2f(m - nm);
    m = nm;
    float rs = 0.f;
#pragma unroll
    for (int tt = 0; tt < 4; tt++)
#pragma unroll
      for (int j = 0; j < 4; j++) {
        float pe = exp2f(sa[tt][j] - nm);
        sa[tt][j] = pe;
        rs += pe;
      }
    rs += __shfl_xor(rs, 16);
    rs += __shfl_xor(rs, 32);
    lsum = lsum * corr + rs;

    // P -> per-wave LDS (packed pairs), then read back as A-fragments
#pragma unroll
    for (int tt = 0; tt < 4; tt++)
#pragma unroll
      for (int pp = 0; pp < 2; pp++) {
        unsigned u = (unsigned)(unsigned short)f2bf(sa[tt][2 * pp]) |
                     ((unsigned)(unsigned short)f2bf(sa[tt][2 * pp + 1]) << 16);
        *(unsigned*)&Ps[w][lr * 72 + tt * 16 + lh * 4 + 2 * pp] = u;
      }

    // rescale po by corr of its own C-row q = lh*4+j
    const float c0 = __shfl(corr, lh * 4 + 0);
    const float c1 = __shfl(corr, lh * 4 + 1);
    const float c2 = __shfl(corr, lh * 4 + 2);
    const float c3 = __shfl(corr, lh * 4 + 3);
#pragma unroll
    for (int n = 0; n < 4; n++) {
      po[n][0] *= c0; po[n][1] *= c1; po[n][2] *= c2; po[n][3] *= c3;
    }

    s16x8 pf0 = *(const s16x8*)&Ps[w][lr * 72 + lh * 8];
    s16x8 pf1 = *(const s16x8*)&Ps[w][lr * 72 + 32 + lh * 8];
#pragma unroll
    for (int n = 0; n < 4; n++) {
#pragma unroll
      for (int kk = 0; kk < 2; kk++) {
        s16x8 vf = *(const s16x8*)&Vts[cur][(n * 16 + lr) * 64 +
                                            ((kk * 32 + lh * 8) ^ ((lr & 7) << 3))];
        po[n] = __builtin_amdgcn_mfma_f32_16x16x32_bf16(kk ? pf1 : pf0, vf, po[n], 0, 0, 0);
      }
    }
    __syncthreads();
    cur ^= 1;
  }

  float linv[4];
#pragma unroll
  for (int j = 0; j < 4; j++) linv[j] = 1.0f / __shfl(lsum, lh * 4 + j);
#pragma unroll
  for (int n = 0; n < 4; n++)
#pragma unroll
    for (int j = 0; j < 4; j++)
      o_ws[((size_t)qb + w * 16 + lh * 4 + j) * 1024 + h * 64 + n * 16 + lr] =
          f2bf(po[n][j] * linv[j]);
}

// ---------------------------------------------------------------------------
extern "C" void kernel_launch(void* const* d_in, const int* in_sizes, int n_in,
                              void* d_out, int out_size, void* d_ws, size_t ws_size,
                              hipStream_t stream) {
  const float* x     = (const float*)d_in[0];
  const float* W_qkv = (const float*)d_in[1];
  const float* b_qkv = (const float*)d_in[2];
  const float* W_out = (const float*)d_in[3];
  const float* b_out = (const float*)d_in[4];
  float* out = (float*)d_out;

  short* R0    = (short*)d_ws;                       // Wqkv_t then O (8MB)
  short* q_ws  = R0 + (size_t)4 * 1024 * 1024;       // 8MB
  short* k_ws  = q_ws + (size_t)4 * 1024 * 1024;     // 8MB
  short* vt_ws = k_ws + (size_t)4 * 1024 * 1024;     // 8MB; Wo_t overlays after attn
  short* Wo_t  = vt_ws;

  // W_qkv [1024][3072] -> Wqkv_t [3072][1024] bf16
  convT_k<<<dim3(48, 16), 256, 0, stream>>>(W_qkv, R0, 1024, 3072);
  // x @ W_qkv + b -> Q / K(swz) / V^T(swz)
  gemm_k<0><<<dim3(32, 24), 256, 0, stream>>>(x, R0, b_qkv, q_ws, k_ws, vt_ws,
                                              nullptr, 3072, 1024);
  // causal flash attention -> O bf16 (overlays Wqkv_t)
  attn_k<<<dim3(64, 16), 256, 0, stream>>>(q_ws, k_ws, vt_ws, R0);
  // W_out -> Wo_t bf16 (overlays dead V^T)
  convT_k<<<dim3(16, 16), 256, 0, stream>>>(W_out, Wo_t, 1024, 1024);
  // O @ W_out + b_out -> f32
  gemm_k<1><<<dim3(32, 8), 256, 0, stream>>>(R0, Wo_t, b_out, nullptr, nullptr,
                                             nullptr, out, 1024, 1024);
}

// Round 3
// 287.737 us; speedup vs baseline: 1.6688x; 1.0601x over previous
//
#include <hip/hip_runtime.h>
#include <cstdint>
#include <cstddef>

// Fused causal self-attention, MI355X gfx950. B=1,S=4096,D=1024,H=16,HD=64.
// ws layout (shorts), 32MB total:
//   R0 @0      : Wqkv_t [3072][1024] bf16 (6MB), later overlaid by O [4096][1024] bf16 (8MB)
//   q  @4M     : Q  [16][4096][64] bf16
//   k  @8M     : K  [16][4096][64] bf16, hd-swizzled: pos = hd ^ ((s&7)<<3)
//   vt @12M    : V^T[16][64][4096] bf16, s-swizzled:  pos = s  ^ ((hd&7)<<3)
//                later overlaid by Wo_t [1024][1024] bf16 (2MB, after attn)
// Pipeline: convT(Wqkv) -> gemm<0> -> attn(32x32 mfma, in-reg P) -> convT(Wout) -> gemm<1>

typedef __attribute__((ext_vector_type(4))) float f32x4;
typedef __attribute__((ext_vector_type(16))) float f32x16;
typedef __attribute__((ext_vector_type(8))) short s16x8;
typedef __attribute__((ext_vector_type(4))) unsigned u32x4;

#define SM_SCALE_LOG2 0.18033688011112042f  // (1/sqrt(64)) * log2(e)

static __device__ __forceinline__ short f2bf(float f) {
  unsigned u = __builtin_bit_cast(unsigned, f);
  u = (u + 0x7fffu + ((u >> 16) & 1u)) >> 16;  // RNE
  return (short)u;
}

static __device__ __forceinline__ unsigned cvtpk(float lo, float hi) {
  unsigned r;
  asm("v_cvt_pk_bf16_f32 %0, %1, %2" : "=v"(r) : "v"(lo), "v"(hi));
  return r;
}

static __device__ __forceinline__ void gload16(const void* g, void* l) {
  __builtin_amdgcn_global_load_lds((const __attribute__((address_space(1))) void*)g,
                                   (__attribute__((address_space(3))) void*)l, 16, 0, 0);
}

// ---------------------------------------------------------------------------
// Convert + transpose: W[K][N] f32 -> Wt[N][K] bf16. 64x64 tiles.
// ---------------------------------------------------------------------------
__global__ __launch_bounds__(256, 2) void convT_k(const float* __restrict__ W,
                                                  short* __restrict__ Wt, int K, int N) {
  __shared__ short T[64][72];
  const int t = threadIdx.x;
  const int n0 = blockIdx.x * 64, k0 = blockIdx.y * 64;
  const int kr = t >> 2, c0 = (t & 3) * 16;
  const float* src = W + (size_t)(k0 + kr) * N + n0 + c0;
  float4 v0 = *(const float4*)(src + 0);
  float4 v1 = *(const float4*)(src + 4);
  float4 v2 = *(const float4*)(src + 8);
  float4 v3 = *(const float4*)(src + 12);
  T[c0 + 0][kr] = f2bf(v0.x);  T[c0 + 1][kr] = f2bf(v0.y);
  T[c0 + 2][kr] = f2bf(v0.z);  T[c0 + 3][kr] = f2bf(v0.w);
  T[c0 + 4][kr] = f2bf(v1.x);  T[c0 + 5][kr] = f2bf(v1.y);
  T[c0 + 6][kr] = f2bf(v1.z);  T[c0 + 7][kr] = f2bf(v1.w);
  T[c0 + 8][kr] = f2bf(v2.x);  T[c0 + 9][kr] = f2bf(v2.y);
  T[c0 + 10][kr] = f2bf(v2.z); T[c0 + 11][kr] = f2bf(v2.w);
  T[c0 + 12][kr] = f2bf(v3.x); T[c0 + 13][kr] = f2bf(v3.y);
  T[c0 + 14][kr] = f2bf(v3.z); T[c0 + 15][kr] = f2bf(v3.w);
  __syncthreads();
  const int nr = t >> 2, kc = (t & 3) * 16;
  s16x8 a = *(const s16x8*)&T[nr][kc];
  s16x8 b = *(const s16x8*)&T[nr][kc + 8];
  short* dst = Wt + (size_t)(n0 + nr) * K + k0 + kc;
  *(s16x8*)dst = a;
  *(s16x8*)(dst + 8) = b;
}

// ---------------------------------------------------------------------------
// GEMM C[M,N] = A[M,K] @ Bt[N,K]^T + bias. 128x128 tile, BK=32, 4 waves 2x2,
// double-buffered LDS, B (and A in MODE 1) staged via global_load_lds.
// MODE 0: A=f32 x (reg-staged cvt), scatter epilogue -> q/k(swz)/vt(swz).
// MODE 1: A=bf16 (gload_lds), f32 out + bias.
// ---------------------------------------------------------------------------
template <int MODE>
__global__ __launch_bounds__(256, 2) void gemm_k(
    const void* __restrict__ Ap, const short* __restrict__ Bt,
    const float* __restrict__ bias,
    short* __restrict__ q_ws, short* __restrict__ k_ws, short* __restrict__ vt_ws,
    float* __restrict__ out, int N, int K) {
  constexpr int LDA = (MODE == 0) ? 40 : 32;
  __shared__ short As[2][128 * LDA];
  __shared__ short Bs[2][128 * 32];

  const int t = threadIdx.x, l = t & 63, w = t >> 6;
  const int wm = (w >> 1) * 64, wn = (w & 1) * 64;
  const int m0 = blockIdx.x * 128, n0 = blockIdx.y * 128;
  const int lr = l & 15, lh = l >> 4;

  f32x4 acc[4][4];
#pragma unroll
  for (int i = 0; i < 4; i++)
#pragma unroll
    for (int j = 0; j < 4; j++) acc[i][j] = (f32x4){0.f, 0.f, 0.f, 0.f};

  const int arow = t >> 1, ac0 = (t & 1) * 16;  // MODE0 A staging map
  const int grow = l >> 2, gc0 = (l & 3) * 8;   // gload lane map: 16 rows / KB

  auto stage = [&](int b, int kt) {
    {
      const int r0 = w * 32;
      const short* s0 = Bt + (size_t)(n0 + r0 + grow) * K + kt + gc0;
      gload16(s0, &Bs[b][r0 * 32]);
      gload16(s0 + (size_t)16 * K, &Bs[b][(r0 + 16) * 32]);
    }
    if constexpr (MODE == 0) {
      const float* ap = (const float*)Ap + (size_t)(m0 + arow) * K + kt + ac0;
      float4 v0 = *(const float4*)(ap + 0);
      float4 v1 = *(const float4*)(ap + 4);
      float4 v2 = *(const float4*)(ap + 8);
      float4 v3 = *(const float4*)(ap + 12);
      s16x8 o0, o1;
      o0[0] = f2bf(v0.x); o0[1] = f2bf(v0.y); o0[2] = f2bf(v0.z); o0[3] = f2bf(v0.w);
      o0[4] = f2bf(v1.x); o0[5] = f2bf(v1.y); o0[6] = f2bf(v1.z); o0[7] = f2bf(v1.w);
      o1[0] = f2bf(v2.x); o1[1] = f2bf(v2.y); o1[2] = f2bf(v2.z); o1[3] = f2bf(v2.w);
      o1[4] = f2bf(v3.x); o1[5] = f2bf(v3.y); o1[6] = f2bf(v3.z); o1[7] = f2bf(v3.w);
      *(s16x8*)&As[b][arow * LDA + ac0] = o0;
      *(s16x8*)&As[b][arow * LDA + ac0 + 8] = o1;
    } else {
      const int r0 = w * 32;
      const short* s0 = (const short*)Ap + (size_t)(m0 + r0 + grow) * K + kt + gc0;
      gload16(s0, &As[b][r0 * 32]);
      gload16(s0 + (size_t)16 * K, &As[b][(r0 + 16) * 32]);
    }
  };

  const int nt = K >> 5;
  stage(0, 0);
  __syncthreads();
  int cur = 0;
  for (int tt = 0; tt < nt; tt++) {
    if (tt + 1 < nt) stage(cur ^ 1, (tt + 1) * 32);
    s16x8 af[4], bfv[4];
#pragma unroll
    for (int mi = 0; mi < 4; mi++)
      af[mi] = *(const s16x8*)&As[cur][(wm + mi * 16 + lr) * LDA + lh * 8];
#pragma unroll
    for (int ni = 0; ni < 4; ni++)
      bfv[ni] = *(const s16x8*)&Bs[cur][(wn + ni * 16 + lr) * 32 + lh * 8];
#pragma unroll
    for (int mi = 0; mi < 4; mi++)
#pragma unroll
      for (int ni = 0; ni < 4; ni++)
        acc[mi][ni] = __builtin_amdgcn_mfma_f32_16x16x32_bf16(af[mi], bfv[ni],
                                                              acc[mi][ni], 0, 0, 0);
    __syncthreads();
    cur ^= 1;
  }

#pragma unroll
  for (int mi = 0; mi < 4; mi++) {
#pragma unroll
    for (int ni = 0; ni < 4; ni++) {
      const int gn = n0 + wn + ni * 16 + lr;
      const float bb = bias[gn];
      if constexpr (MODE == 0) {
        const int sect = gn >> 10, dd = gn & 1023, hh = dd >> 6, hd = dd & 63;
#pragma unroll
        for (int j = 0; j < 4; j++) {
          const int gm = m0 + wm + mi * 16 + lh * 4 + j;  // token s
          const short bv = f2bf(acc[mi][ni][j] + bb);
          if (sect == 0)
            q_ws[((size_t)hh * 4096 + gm) * 64 + hd] = bv;
          else if (sect == 1)
            k_ws[((size_t)hh * 4096 + gm) * 64 + (hd ^ ((gm & 7) << 3))] = bv;
          else
            vt_ws[((size_t)hh * 64 + hd) * 4096 + (gm ^ ((hd & 7) << 3))] = bv;
        }
      } else {
#pragma unroll
        for (int j = 0; j < 4; j++) {
          const int gm = m0 + wm + mi * 16 + lh * 4 + j;
          out[(size_t)gm * N + gn] = acc[mi][ni][j] + bb;
        }
      }
    }
  }
}

// ---------------------------------------------------------------------------
// Flash attention v3: 32x32x16 MFMA, swapped QK^T (S^T = K Q^T), softmax
// fully in-lane (q = lane&31), P->A-frag via cvt_pk + shfl_xor(32) exchange
// (no LDS round trip). Block = 2 waves x 32 q-rows = 64 q. KV tile 64,
// double-buffered LDS via global_load_lds from pre-swizzled K / V^T.
// Load balance: qbi = (head<8) ? x : 63-x -> per-CU-slot work is constant.
// ---------------------------------------------------------------------------
__global__ __launch_bounds__(128, 2) void attn_k(
    const short* __restrict__ q_ws, const short* __restrict__ k_ws,
    const short* __restrict__ vt_ws, short* __restrict__ o_ws) {
  __shared__ short Ks[2][64 * 64];
  __shared__ short Vts[2][64 * 64];

  const int t = threadIdx.x, l = t & 63, w = t >> 6;  // w in {0,1}
  const int ql = l & 31, hi = l >> 5;
  const int h = blockIdx.y;
  const int qbi = (h < 8) ? (int)blockIdx.x : 63 - (int)blockIdx.x;
  const int qb = qbi * 64;
  const int q0w = qb + w * 32;
  const int qg = q0w + ql;  // this lane's q row (global), also softmax owner
  const int nkv = qbi + 1;

  // Q B-fragments: lane (ql,hi) holds Q[qg][ks*16 + hi*8 + j]
  s16x8 qf[4];
  {
    const short* qp = q_ws + ((size_t)h * 4096 + qg) * 64 + hi * 8;
#pragma unroll
    for (int ks = 0; ks < 4; ks++) qf[ks] = *(const s16x8*)(qp + ks * 16);
  }

  f32x16 po0, po1;  // O accumulators, C-layout: col=d(ql), row=q
#pragma unroll
  for (int r = 0; r < 16; r++) { po0[r] = 0.f; po1[r] = 0.f; }
  float m = -1e30f, lsum = 0.f;

  const int srow = l >> 3, scol = (l & 7) * 8;
  auto stage = [&](int b, int kv0) {
    const short* kp = k_ws + ((size_t)h * 4096 + kv0 + w * 32 + srow) * 64 + scol;
    const short* vp = vt_ws + ((size_t)h * 64 + w * 32 + srow) * 4096 + kv0 + scol;
#pragma unroll
    for (int i = 0; i < 4; i++) {
      gload16(kp + (size_t)(8 * i) * 64, &Ks[b][(w * 32 + 8 * i) * 64]);
      gload16(vp + (size_t)(8 * i) * 4096, &Vts[b][(w * 32 + 8 * i) * 64]);
    }
  };

  stage(0, 0);
  __syncthreads();
  int cur = 0;
  for (int kt = 0; kt < nkv; kt++) {
    const int kv0 = kt * 64;
    if (kt + 1 < nkv) stage(cur ^ 1, kv0 + 64);

    // ---- QK^T swapped: sa = S^T (col = q = ql, row = kv) ----
    f32x16 sa0, sa1;
#pragma unroll
    for (int r = 0; r < 16; r++) { sa0[r] = 0.f; sa1[r] = 0.f; }
#pragma unroll
    for (int ks = 0; ks < 4; ks++) {
      const int co = (ks * 16 + hi * 8) ^ ((ql & 7) << 3);
      s16x8 kf0 = *(const s16x8*)&Ks[cur][ql * 64 + co];
      s16x8 kf1 = *(const s16x8*)&Ks[cur][(32 + ql) * 64 + co];
      sa0 = __builtin_amdgcn_mfma_f32_32x32x16_bf16(kf0, qf[ks], sa0, 0, 0, 0);
      sa1 = __builtin_amdgcn_mfma_f32_32x32x16_bf16(kf1, qf[ks], sa1, 0, 0, 0);
    }

    // ---- causal mask (only near-diagonal tiles take this branch) ----
    if (kv0 + 63 > q0w) {
#pragma unroll
      for (int r = 0; r < 16; r++) {
        const int kvl = (r & 3) + 8 * (r >> 2) + 4 * hi;
        if (kv0 + kvl > qg) sa0[r] = -3e38f;
        if (kv0 + 32 + kvl > qg) sa1[r] = -3e38f;
      }
    }

    // ---- online softmax (log2 domain, scale folded into fma) ----
    float a[8];
#pragma unroll
    for (int i = 0; i < 8; i++)
      a[i] = fmaxf(fmaxf(sa0[i], sa0[i + 8]), fmaxf(sa1[i], sa1[i + 8]));
#pragma unroll
    for (int i = 0; i < 4; i++) a[i] = fmaxf(a[i], a[i + 4]);
    float pm = fmaxf(fmaxf(a[0], a[1]), fmaxf(a[2], a[3]));
    pm = fmaxf(pm, __shfl_xor(pm, 32));
    pm *= SM_SCALE_LOG2;

    const bool defer = __all(pm <= m + 8.0f) != 0;  // T13 defer-max
    if (!defer) {
      const float nm = fmaxf(m, pm);
      const float corr = exp2f(m - nm);
      m = nm;
      lsum *= corr;
#pragma unroll
      for (int r = 0; r < 16; r++) {
        const int qr = (r & 3) + 8 * (r >> 2) + 4 * hi;
        const float cq = __shfl(corr, qr);
        po0[r] *= cq;
        po1[r] *= cq;
      }
    }

    float e0[16], e1[16];
#pragma unroll
    for (int r = 0; r < 16; r++) {
      e0[r] = exp2f(__builtin_fmaf(sa0[r], SM_SCALE_LOG2, -m));
      e1[r] = exp2f(__builtin_fmaf(sa1[r], SM_SCALE_LOG2, -m));
    }
    float s[8];
#pragma unroll
    for (int i = 0; i < 8; i++) s[i] = (e0[i] + e0[i + 8]) + (e1[i] + e1[i + 8]);
#pragma unroll
    for (int i = 0; i < 4; i++) s[i] += s[i + 4];
    float rs = (s[0] + s[1]) + (s[2] + s[3]);
    rs += __shfl_xor(rs, 32);
    lsum += rs;

    // ---- P (f32 C-layout) -> bf16 A-frags, in-register (T12 structure) ----
    unsigned pk0[8], pk1[8], sx0[8], sx1[8];
#pragma unroll
    for (int g = 0; g < 8; g++) {
      pk0[g] = cvtpk(e0[2 * g], e0[2 * g + 1]);
      pk1[g] = cvtpk(e1[2 * g], e1[2 * g + 1]);
      sx0[g] = (unsigned)__shfl_xor((int)pk0[g], 32);
      sx1[g] = (unsigned)__shfl_xor((int)pk1[g], 32);
    }

    // ---- PV: po += P @ V ----
#pragma unroll
    for (int ks = 0; ks < 4; ks++) {
      const int B = 4 * (ks & 1);
      u32x4 pw;
      if (ks >> 1) {
        pw[0] = hi ? sx1[B + 2] : pk1[B + 0];
        pw[1] = hi ? sx1[B + 3] : pk1[B + 1];
        pw[2] = hi ? pk1[B + 2] : sx1[B + 0];
        pw[3] = hi ? pk1[B + 3] : sx1[B + 1];
      } else {
        pw[0] = hi ? sx0[B + 2] : pk0[B + 0];
        pw[1] = hi ? sx0[B + 3] : pk0[B + 1];
        pw[2] = hi ? pk0[B + 2] : sx0[B + 0];
        pw[3] = hi ? pk0[B + 3] : sx0[B + 1];
      }
      const s16x8 paf = __builtin_bit_cast(s16x8, pw);
      const int co = (ks * 16 + hi * 8) ^ ((ql & 7) << 3);
      s16x8 vf0 = *(const s16x8*)&Vts[cur][ql * 64 + co];
      s16x8 vf1 = *(const s16x8*)&Vts[cur][(32 + ql) * 64 + co];
      po0 = __builtin_amdgcn_mfma_f32_32x32x16_bf16(paf, vf0, po0, 0, 0, 0);
      po1 = __builtin_amdgcn_mfma_f32_32x32x16_bf16(paf, vf1, po1, 0, 0, 0);
    }

    __syncthreads();
    cur ^= 1;
  }

  // ---- epilogue: O[q][d] = po / lsum(q) ----
  const float li = 1.0f / lsum;
#pragma unroll
  for (int r = 0; r < 16; r++) {
    const int qr = (r & 3) + 8 * (r >> 2) + 4 * hi;
    const float lq = __shfl(li, qr);
    const size_t row = (size_t)(qb + w * 32 + qr);
    o_ws[row * 1024 + h * 64 + ql] = f2bf(po0[r] * lq);
    o_ws[row * 1024 + h * 64 + 32 + ql] = f2bf(po1[r] * lq);
  }
}

// ---------------------------------------------------------------------------
extern "C" void kernel_launch(void* const* d_in, const int* in_sizes, int n_in,
                              void* d_out, int out_size, void* d_ws, size_t ws_size,
                              hipStream_t stream) {
  const float* x     = (const float*)d_in[0];
  const float* W_qkv = (const float*)d_in[1];
  const float* b_qkv = (const float*)d_in[2];
  const float* W_out = (const float*)d_in[3];
  const float* b_out = (const float*)d_in[4];
  float* out = (float*)d_out;

  short* R0    = (short*)d_ws;                       // Wqkv_t then O (8MB)
  short* q_ws  = R0 + (size_t)4 * 1024 * 1024;       // 8MB
  short* k_ws  = q_ws + (size_t)4 * 1024 * 1024;     // 8MB
  short* vt_ws = k_ws + (size_t)4 * 1024 * 1024;     // 8MB; Wo_t overlays after attn
  short* Wo_t  = vt_ws;

  // W_qkv [1024][3072] -> Wqkv_t [3072][1024] bf16
  convT_k<<<dim3(48, 16), 256, 0, stream>>>(W_qkv, R0, 1024, 3072);
  // x @ W_qkv + b -> Q / K(swz) / V^T(swz)
  gemm_k<0><<<dim3(32, 24), 256, 0, stream>>>(x, R0, b_qkv, q_ws, k_ws, vt_ws,
                                              nullptr, 3072, 1024);
  // causal flash attention -> O bf16 (overlays Wqkv_t)
  attn_k<<<dim3(64, 16), 128, 0, stream>>>(q_ws, k_ws, vt_ws, R0);
  // W_out -> Wo_t bf16 (overlays dead V^T)
  convT_k<<<dim3(16, 16), 256, 0, stream>>>(W_out, Wo_t, 1024, 1024);
  // O @ W_out + b_out -> f32
  gemm_k<1><<<dim3(32, 8), 256, 0, stream>>>(R0, Wo_t, b_out, nullptr, nullptr,
                                             nullptr, out, 1024, 1024);
}

// Round 4
// 267.856 us; speedup vs baseline: 1.7926x; 1.0742x over previous
//
#include <hip/hip_runtime.h>
#include <cstdint>
#include <cstddef>

// Fused causal self-attention, MI355X gfx950. B=1,S=4096,D=1024,H=16,HD=64.
// ws layout (shorts), base 32MB + optional 8MB:
//   R0 @0    : Wqkv_t [3072][1024] bf16 (6MB), later overlaid by O [4096][1024] bf16 (8MB)
//   q  @4M   : Q  [16][4096][64] bf16
//   k  @8M   : K  [16][4096][64] bf16, hd-swizzled: pos = hd ^ ((s&7)<<3)
//   vt @12M  : V^T[16][64][4096] bf16, s-swizzled:  pos = s  ^ ((hd&7)<<3)
//              later overlaid by Wo_t [1024][1024] bf16 (after attn)
//   xbf @16M (elems): x as bf16 [4096][1024] -- only if ws_size >= 40MB
// Pipeline: [convx] convT(Wqkv) -> gemm<qkv> -> attn -> convT(Wout) -> gemm<out>

typedef __attribute__((ext_vector_type(4))) float f32x4;
typedef __attribute__((ext_vector_type(16))) float f32x16;
typedef __attribute__((ext_vector_type(8))) short s16x8;
typedef __attribute__((ext_vector_type(4))) unsigned u32x4;

#define SM_SCALE_LOG2 0.18033688011112042f  // (1/sqrt(64)) * log2(e)

static __device__ __forceinline__ short f2bf(float f) {
  unsigned u = __builtin_bit_cast(unsigned, f);
  u = (u + 0x7fffu + ((u >> 16) & 1u)) >> 16;  // RNE
  return (short)u;
}

static __device__ __forceinline__ unsigned cvtpk(float lo, float hi) {
  unsigned r;
  asm("v_cvt_pk_bf16_f32 %0, %1, %2" : "=v"(r) : "v"(lo), "v"(hi));
  return r;
}

static __device__ __forceinline__ void gload16(const void* g, void* l) {
  __builtin_amdgcn_global_load_lds((const __attribute__((address_space(1))) void*)g,
                                   (__attribute__((address_space(3))) void*)l, 16, 0, 0);
}

// ---------------------------------------------------------------------------
// x [M][K] f32 -> bf16 (pure bandwidth)
// ---------------------------------------------------------------------------
__global__ __launch_bounds__(256) void convx_k(const float* __restrict__ x,
                                               short* __restrict__ xb) {
  const size_t i = ((size_t)blockIdx.x * 256 + threadIdx.x) * 8;
  float4 a = *(const float4*)(x + i);
  float4 b = *(const float4*)(x + i + 4);
  u32x4 p;
  p[0] = cvtpk(a.x, a.y); p[1] = cvtpk(a.z, a.w);
  p[2] = cvtpk(b.x, b.y); p[3] = cvtpk(b.z, b.w);
  *(u32x4*)(xb + i) = p;
}

// ---------------------------------------------------------------------------
// Convert + transpose: W[K][N] f32 -> Wt[N][K] bf16. 64x64 tiles.
// ---------------------------------------------------------------------------
__global__ __launch_bounds__(256, 2) void convT_k(const float* __restrict__ W,
                                                  short* __restrict__ Wt, int K, int N) {
  __shared__ short T[64][72];
  const int t = threadIdx.x;
  const int n0 = blockIdx.x * 64, k0 = blockIdx.y * 64;
  const int kr = t >> 2, c0 = (t & 3) * 16;
  const float* src = W + (size_t)(k0 + kr) * N + n0 + c0;
  float4 v0 = *(const float4*)(src + 0);
  float4 v1 = *(const float4*)(src + 4);
  float4 v2 = *(const float4*)(src + 8);
  float4 v3 = *(const float4*)(src + 12);
  T[c0 + 0][kr] = f2bf(v0.x);  T[c0 + 1][kr] = f2bf(v0.y);
  T[c0 + 2][kr] = f2bf(v0.z);  T[c0 + 3][kr] = f2bf(v0.w);
  T[c0 + 4][kr] = f2bf(v1.x);  T[c0 + 5][kr] = f2bf(v1.y);
  T[c0 + 6][kr] = f2bf(v1.z);  T[c0 + 7][kr] = f2bf(v1.w);
  T[c0 + 8][kr] = f2bf(v2.x);  T[c0 + 9][kr] = f2bf(v2.y);
  T[c0 + 10][kr] = f2bf(v2.z); T[c0 + 11][kr] = f2bf(v2.w);
  T[c0 + 12][kr] = f2bf(v3.x); T[c0 + 13][kr] = f2bf(v3.y);
  T[c0 + 14][kr] = f2bf(v3.z); T[c0 + 15][kr] = f2bf(v3.w);
  __syncthreads();
  const int nr = t >> 2, kc = (t & 3) * 16;
  s16x8 a = *(const s16x8*)&T[nr][kc];
  s16x8 b = *(const s16x8*)&T[nr][kc + 8];
  short* dst = Wt + (size_t)(n0 + nr) * K + k0 + kc;
  *(s16x8*)dst = a;
  *(s16x8*)(dst + 8) = b;
}

// ---------------------------------------------------------------------------
// GEMM C[M,N] = A[M,K] @ Bt[N,K]^T + bias. 128x128 tile, BK=32, 4 waves 2x2,
// double-buffered LDS, gload_lds staging for B (and A when ABF=1).
// ABF: 1 = A bf16 (gload_lds), 0 = A f32 (reg cvt_pk staging).
// SCAT: 1 = scatter epilogue -> q/k(swz)/vt(swz), 0 = f32 out + bias.
// ---------------------------------------------------------------------------
template <int ABF, int SCAT>
__global__ __launch_bounds__(256, 2) void gemm_k(
    const void* __restrict__ Ap, const short* __restrict__ Bt,
    const float* __restrict__ bias,
    short* __restrict__ q_ws, short* __restrict__ k_ws, short* __restrict__ vt_ws,
    float* __restrict__ out, int N, int K) {
  constexpr int LDA = ABF ? 32 : 40;
  __shared__ short As[2][128 * LDA];
  __shared__ short Bs[2][128 * 32];

  const int t = threadIdx.x, l = t & 63, w = t >> 6;
  const int wm = (w >> 1) * 64, wn = (w & 1) * 64;
  const int m0 = blockIdx.x * 128, n0 = blockIdx.y * 128;
  const int lr = l & 15, lh = l >> 4;

  f32x4 acc[4][4];
#pragma unroll
  for (int i = 0; i < 4; i++)
#pragma unroll
    for (int j = 0; j < 4; j++) acc[i][j] = (f32x4){0.f, 0.f, 0.f, 0.f};

  const int arow = t >> 1, ac0 = (t & 1) * 16;  // ABF=0 A staging map
  const int grow = l >> 2, gc0 = (l & 3) * 8;   // gload lane map: 16 rows / KB

  auto stage = [&](int b, int kt) {
    {
      const int r0 = w * 32;
      const short* s0 = Bt + (size_t)(n0 + r0 + grow) * K + kt + gc0;
      gload16(s0, &Bs[b][r0 * 32]);
      gload16(s0 + (size_t)16 * K, &Bs[b][(r0 + 16) * 32]);
    }
    if constexpr (ABF) {
      const int r0 = w * 32;
      const short* s0 = (const short*)Ap + (size_t)(m0 + r0 + grow) * K + kt + gc0;
      gload16(s0, &As[b][r0 * 32]);
      gload16(s0 + (size_t)16 * K, &As[b][(r0 + 16) * 32]);
    } else {
      const float* ap = (const float*)Ap + (size_t)(m0 + arow) * K + kt + ac0;
      float4 v0 = *(const float4*)(ap + 0);
      float4 v1 = *(const float4*)(ap + 4);
      float4 v2 = *(const float4*)(ap + 8);
      float4 v3 = *(const float4*)(ap + 12);
      u32x4 p0, p1;
      p0[0] = cvtpk(v0.x, v0.y); p0[1] = cvtpk(v0.z, v0.w);
      p0[2] = cvtpk(v1.x, v1.y); p0[3] = cvtpk(v1.z, v1.w);
      p1[0] = cvtpk(v2.x, v2.y); p1[1] = cvtpk(v2.z, v2.w);
      p1[2] = cvtpk(v3.x, v3.y); p1[3] = cvtpk(v3.z, v3.w);
      *(u32x4*)&As[b][arow * LDA + ac0] = p0;
      *(u32x4*)&As[b][arow * LDA + ac0 + 8] = p1;
    }
  };

  const int nt = K >> 5;
  stage(0, 0);
  __syncthreads();
  int cur = 0;
  for (int tt = 0; tt < nt; tt++) {
    if (tt + 1 < nt) stage(cur ^ 1, (tt + 1) * 32);
    s16x8 af[4], bfv[4];
#pragma unroll
    for (int mi = 0; mi < 4; mi++)
      af[mi] = *(const s16x8*)&As[cur][(wm + mi * 16 + lr) * LDA + lh * 8];
#pragma unroll
    for (int ni = 0; ni < 4; ni++)
      bfv[ni] = *(const s16x8*)&Bs[cur][(wn + ni * 16 + lr) * 32 + lh * 8];
#pragma unroll
    for (int mi = 0; mi < 4; mi++)
#pragma unroll
      for (int ni = 0; ni < 4; ni++)
        acc[mi][ni] = __builtin_amdgcn_mfma_f32_16x16x32_bf16(af[mi], bfv[ni],
                                                              acc[mi][ni], 0, 0, 0);
    __syncthreads();
    cur ^= 1;
  }

#pragma unroll
  for (int mi = 0; mi < 4; mi++) {
#pragma unroll
    for (int ni = 0; ni < 4; ni++) {
      const int gn = n0 + wn + ni * 16 + lr;
      const float bb = bias[gn];
      if constexpr (SCAT) {
        const int sect = gn >> 10, dd = gn & 1023, hh = dd >> 6, hd = dd & 63;
#pragma unroll
        for (int j = 0; j < 4; j++) {
          const int gm = m0 + wm + mi * 16 + lh * 4 + j;  // token s
          const short bv = f2bf(acc[mi][ni][j] + bb);
          if (sect == 0)
            q_ws[((size_t)hh * 4096 + gm) * 64 + hd] = bv;
          else if (sect == 1)
            k_ws[((size_t)hh * 4096 + gm) * 64 + (hd ^ ((gm & 7) << 3))] = bv;
          else
            vt_ws[((size_t)hh * 64 + hd) * 4096 + (gm ^ ((hd & 7) << 3))] = bv;
        }
      } else {
#pragma unroll
        for (int j = 0; j < 4; j++) {
          const int gm = m0 + wm + mi * 16 + lh * 4 + j;
          out[(size_t)gm * N + gn] = acc[mi][ni][j] + bb;
        }
      }
    }
  }
}

// ---------------------------------------------------------------------------
// Flash attention v4: 32x32x16 MFMA, swapped QK^T, in-register P (cvt_pk +
// shfl_xor(32)), T15 shift-pipeline: region {QK(t+1) || PV(t) || softmax(t+1)}
// with ONE barrier per tile and triple-buffered K/V LDS (gload_lds staging,
// stage(t+2) issued right after the barrier -> full-tile latency cover).
// Block = 4 waves x 32 q-rows = 128 q. Balance: bq = (h<8)? x : 31-x.
// ---------------------------------------------------------------------------
__global__ __launch_bounds__(256, 2) void attn_k(
    const short* __restrict__ q_ws, const short* __restrict__ k_ws,
    const short* __restrict__ vt_ws, short* __restrict__ o_ws) {
  __shared__ short Ks[3][64 * 64];
  __shared__ short Vts[3][64 * 64];

  const int t = threadIdx.x, l = t & 63, w = t >> 6;  // w in 0..3
  const int ql = l & 31, hi = l >> 5;
  const int h = blockIdx.y;
  const int bq = (h < 8) ? (int)blockIdx.x : 31 - (int)blockIdx.x;
  const int QB = bq * 128;
  const int q0w = QB + 32 * w;
  const int qg = q0w + ql;       // this lane's q row; softmax owner
  const int nkv = 2 * bq + 2;

  // Q B-fragments: lane (ql,hi) holds Q[qg][ks*16 + hi*8 + j]
  s16x8 qf[4];
  {
    const short* qp = q_ws + ((size_t)h * 4096 + qg) * 64 + hi * 8;
#pragma unroll
    for (int ks = 0; ks < 4; ks++) qf[ks] = *(const s16x8*)(qp + ks * 16);
  }

  f32x16 po0, po1;
#pragma unroll
  for (int r = 0; r < 16; r++) { po0[r] = 0.f; po1[r] = 0.f; }
  float m = -1e30f, lsum = 0.f;
  s16x8 paf[4];  // P(t) A-fragments, built one tile ahead

  const int sr = l >> 3, sc = (l & 7) * 8;
  auto stage = [&](int b, int kv0) {
#pragma unroll
    for (int i = 0; i < 2; i++) {
      const int r = 16 * w + 8 * i + sr;
      gload16(k_ws + ((size_t)h * 4096 + kv0 + r) * 64 + sc, &Ks[b][(16 * w + 8 * i) * 64]);
      gload16(vt_ws + ((size_t)h * 64 + r) * 4096 + kv0 + sc, &Vts[b][(16 * w + 8 * i) * 64]);
    }
  };

  // QK^T (swapped) + online softmax + build P A-frags for tile at kv0, buf b.
  auto qk_sm = [&](int kv0, int b) {
    f32x16 sa0, sa1;
#pragma unroll
    for (int r = 0; r < 16; r++) { sa0[r] = 0.f; sa1[r] = 0.f; }
#pragma unroll
    for (int ks = 0; ks < 4; ks++) {
      const int co = (ks * 16 + hi * 8) ^ ((ql & 7) << 3);
      s16x8 kf0 = *(const s16x8*)&Ks[b][ql * 64 + co];
      s16x8 kf1 = *(const s16x8*)&Ks[b][(32 + ql) * 64 + co];
      sa0 = __builtin_amdgcn_mfma_f32_32x32x16_bf16(kf0, qf[ks], sa0, 0, 0, 0);
      sa1 = __builtin_amdgcn_mfma_f32_32x32x16_bf16(kf1, qf[ks], sa1, 0, 0, 0);
    }
    if (kv0 + 63 > q0w) {  // causal mask (near-diagonal tiles only)
#pragma unroll
      for (int r = 0; r < 16; r++) {
        const int kvl = (r & 3) + 8 * (r >> 2) + 4 * hi;
        if (kv0 + kvl > qg) sa0[r] = -3e38f;
        if (kv0 + 32 + kvl > qg) sa1[r] = -3e38f;
      }
    }
    float a[8];
#pragma unroll
    for (int i = 0; i < 8; i++)
      a[i] = fmaxf(fmaxf(sa0[i], sa0[i + 8]), fmaxf(sa1[i], sa1[i + 8]));
#pragma unroll
    for (int i = 0; i < 4; i++) a[i] = fmaxf(a[i], a[i + 4]);
    float pm = fmaxf(fmaxf(a[0], a[1]), fmaxf(a[2], a[3]));
    pm = fmaxf(pm, __shfl_xor(pm, 32));
    pm *= SM_SCALE_LOG2;

    const bool defer = __all(pm <= m + 8.0f) != 0;  // T13
    if (!defer) {
      const float nm = fmaxf(m, pm);
      const float corr = exp2f(m - nm);
      m = nm;
      lsum *= corr;
#pragma unroll
      for (int r = 0; r < 16; r++) {
        const int qr = (r & 3) + 8 * (r >> 2) + 4 * hi;
        const float cq = __shfl(corr, qr);
        po0[r] *= cq;
        po1[r] *= cq;
      }
    }

    float e0[16], e1[16];
#pragma unroll
    for (int r = 0; r < 16; r++) {
      e0[r] = exp2f(__builtin_fmaf(sa0[r], SM_SCALE_LOG2, -m));
      e1[r] = exp2f(__builtin_fmaf(sa1[r], SM_SCALE_LOG2, -m));
    }
    float s[8];
#pragma unroll
    for (int i = 0; i < 8; i++) s[i] = (e0[i] + e0[i + 8]) + (e1[i] + e1[i + 8]);
#pragma unroll
    for (int i = 0; i < 4; i++) s[i] += s[i + 4];
    float rs = (s[0] + s[1]) + (s[2] + s[3]);
    rs += __shfl_xor(rs, 32);
    lsum += rs;

    unsigned pk0[8], pk1[8], sx0[8], sx1[8];
#pragma unroll
    for (int g = 0; g < 8; g++) {
      pk0[g] = cvtpk(e0[2 * g], e0[2 * g + 1]);
      pk1[g] = cvtpk(e1[2 * g], e1[2 * g + 1]);
      sx0[g] = (unsigned)__shfl_xor((int)pk0[g], 32);
      sx1[g] = (unsigned)__shfl_xor((int)pk1[g], 32);
    }
#pragma unroll
    for (int ks = 0; ks < 4; ks++) {
      const int B = 4 * (ks & 1);
      u32x4 pw;
      if (ks >> 1) {
        pw[0] = hi ? sx1[B + 2] : pk1[B + 0];
        pw[1] = hi ? sx1[B + 3] : pk1[B + 1];
        pw[2] = hi ? pk1[B + 2] : sx1[B + 0];
        pw[3] = hi ? pk1[B + 3] : sx1[B + 1];
      } else {
        pw[0] = hi ? sx0[B + 2] : pk0[B + 0];
        pw[1] = hi ? sx0[B + 3] : pk0[B + 1];
        pw[2] = hi ? pk0[B + 2] : sx0[B + 0];
        pw[3] = hi ? pk0[B + 3] : sx0[B + 1];
      }
      paf[ks] = __builtin_bit_cast(s16x8, pw);
    }
  };

  // ---- prologue: stage(0), stage(1), P(0) ----
  stage(0, 0);
  __syncthreads();
  stage(1, 64);
  qk_sm(0, 0);  // tile 0 is active for every wave

  int bc = 0, bn = 1, bs = 2;
  bool actC = true;
  for (int tt = 0; tt < nkv; tt++) {
    __syncthreads();  // drains own gloads (stage tt+1) + cross-wave visibility
    __builtin_amdgcn_s_setprio(1);
    if (tt + 2 < nkv) stage(bs, 64 * (tt + 2));
    const bool actN = (tt + 1 < nkv) && (64 * (tt + 1) <= q0w + 31);
    // PV(tt) — two independent MFMA chains vs QK inside qk_sm; po rescale
    // (inside qk_sm) is data-dep ordered AFTER these accumulates.
    if (actC) {
#pragma unroll
      for (int ks = 0; ks < 4; ks++) {
        const int co = (ks * 16 + hi * 8) ^ ((ql & 7) << 3);
        s16x8 vf0 = *(const s16x8*)&Vts[bc][ql * 64 + co];
        s16x8 vf1 = *(const s16x8*)&Vts[bc][(32 + ql) * 64 + co];
        po0 = __builtin_amdgcn_mfma_f32_32x32x16_bf16(paf[ks], vf0, po0, 0, 0, 0);
        po1 = __builtin_amdgcn_mfma_f32_32x32x16_bf16(paf[ks], vf1, po1, 0, 0, 0);
      }
    }
    if (actN) qk_sm(64 * (tt + 1), bn);
    __builtin_amdgcn_s_setprio(0);
    actC = actN;
    const int old = bc; bc = bn; bn = bs; bs = old;
  }

  // ---- epilogue: O[q][d] = po / lsum(q) ----
  const float li = 1.0f / lsum;
#pragma unroll
  for (int r = 0; r < 16; r++) {
    const int qr = (r & 3) + 8 * (r >> 2) + 4 * hi;
    const float lq = __shfl(li, qr);
    const size_t row = (size_t)(q0w + qr);
    o_ws[row * 1024 + h * 64 + ql] = f2bf(po0[r] * lq);
    o_ws[row * 1024 + h * 64 + 32 + ql] = f2bf(po1[r] * lq);
  }
}

// ---------------------------------------------------------------------------
extern "C" void kernel_launch(void* const* d_in, const int* in_sizes, int n_in,
                              void* d_out, int out_size, void* d_ws, size_t ws_size,
                              hipStream_t stream) {
  const float* x     = (const float*)d_in[0];
  const float* W_qkv = (const float*)d_in[1];
  const float* b_qkv = (const float*)d_in[2];
  const float* W_out = (const float*)d_in[3];
  const float* b_out = (const float*)d_in[4];
  float* out = (float*)d_out;

  short* R0    = (short*)d_ws;                     // Wqkv_t then O (8MB)
  short* q_ws  = R0 + (size_t)4 * 1024 * 1024;
  short* k_ws  = q_ws + (size_t)4 * 1024 * 1024;
  short* vt_ws = k_ws + (size_t)4 * 1024 * 1024;
  short* Wo_t  = vt_ws;                            // overlays V^T after attn
  short* xbf   = vt_ws + (size_t)4 * 1024 * 1024;  // optional +8MB region

  const bool big_ws = ws_size >= (size_t)40 * 1024 * 1024;

  // W_qkv [1024][3072] -> Wqkv_t [3072][1024] bf16
  convT_k<<<dim3(48, 16), 256, 0, stream>>>(W_qkv, R0, 1024, 3072);
  if (big_ws) {
    convx_k<<<2048, 256, 0, stream>>>(x, xbf);  // x -> bf16 (DMA-stageable A)
    gemm_k<1, 1><<<dim3(32, 24), 256, 0, stream>>>(xbf, R0, b_qkv, q_ws, k_ws,
                                                   vt_ws, nullptr, 3072, 1024);
  } else {
    gemm_k<0, 1><<<dim3(32, 24), 256, 0, stream>>>(x, R0, b_qkv, q_ws, k_ws,
                                                   vt_ws, nullptr, 3072, 1024);
  }
  // causal flash attention -> O bf16 (overlays Wqkv_t)
  attn_k<<<dim3(32, 16), 256, 0, stream>>>(q_ws, k_ws, vt_ws, R0);
  // W_out -> Wo_t bf16 (overlays dead V^T)
  convT_k<<<dim3(16, 16), 256, 0, stream>>>(W_out, Wo_t, 1024, 1024);
  // O @ W_out + b_out -> f32
  gemm_k<1, 0><<<dim3(32, 8), 256, 0, stream>>>(R0, Wo_t, b_out, nullptr, nullptr,
                                                nullptr, out, 1024, 1024);
}

// Round 5
// 251.067 us; speedup vs baseline: 1.9125x; 1.0669x over previous
//
#include <hip/hip_runtime.h>
#include <cstdint>
#include <cstddef>

// Fused causal self-attention, MI355X gfx950. B=1,S=4096,D=1024,H=16,HD=64.
// ws layout (shorts), base 32MB + optional 8MB:
//   R0 @0    : Wqkv_t [3072][1024] bf16 (6MB), later overlaid by O [4096][1024] bf16 (8MB)
//   q  @4M   : Q  [16][4096][64] bf16
//   k  @8M   : K  [16][128][32][64] bf16 (tile-contiguous: [h][kvtile][kv32][hd64])
//   vt @12M  : V^T [16][128][64][32] bf16 (tile-contiguous: [h][kvtile][hd64][kv32])
//              later overlaid by Wo_t [1024][1024] bf16 (after attn)
//   xbf @16M (elems): x as bf16 [4096][1024] -- only if ws_size >= 40MB
// attn v5: barrier-free main loop, global->VGPR operands, kv-split x4 per strip,
// LDS only for the per-strip 4-way combine.

typedef __attribute__((ext_vector_type(4))) float f32x4;
typedef __attribute__((ext_vector_type(16))) float f32x16;
typedef __attribute__((ext_vector_type(8))) short s16x8;
typedef __attribute__((ext_vector_type(4))) unsigned u32x4;

#define SM_SCALE_LOG2 0.18033688011112042f  // (1/sqrt(64)) * log2(e)

#if __has_builtin(__builtin_amdgcn_exp2f)
#define EXP2(x) __builtin_amdgcn_exp2f(x)
#else
#define EXP2(x) exp2f(x)
#endif

static __device__ __forceinline__ short f2bf(float f) {
  unsigned u = __builtin_bit_cast(unsigned, f);
  u = (u + 0x7fffu + ((u >> 16) & 1u)) >> 16;  // RNE
  return (short)u;
}

static __device__ __forceinline__ unsigned cvtpk(float lo, float hi) {
  unsigned r;
  asm("v_cvt_pk_bf16_f32 %0, %1, %2" : "=v"(r) : "v"(lo), "v"(hi));
  return r;
}

// a' = {a.lanes0-31 || b.lanes0-31}, b' = {a.lanes32-63 || b.lanes32-63}
static __device__ __forceinline__ void plswap(unsigned& a, unsigned& b) {
#if __has_builtin(__builtin_amdgcn_permlane32_swap)
  auto r = __builtin_amdgcn_permlane32_swap((int)a, (int)b, false, false);
  unsigned tmp[2];
  __builtin_memcpy(tmp, &r, 8);
  a = tmp[0];
  b = tmp[1];
#else
  const unsigned xa = (unsigned)__shfl_xor((int)a, 32);
  const unsigned xb = (unsigned)__shfl_xor((int)b, 32);
  const bool hiL = (threadIdx.x & 32) != 0;
  const unsigned na = hiL ? xb : a;
  const unsigned nb = hiL ? b : xa;
  a = na;
  b = nb;
#endif
}

static __device__ __forceinline__ void gload16(const void* g, void* l) {
  __builtin_amdgcn_global_load_lds((const __attribute__((address_space(1))) void*)g,
                                   (__attribute__((address_space(3))) void*)l, 16, 0, 0);
}

#define MFMA32(A, B, C) __builtin_amdgcn_mfma_f32_32x32x16_bf16(A, B, C, 0, 0, 0)

// ---------------------------------------------------------------------------
// x [M][K] f32 -> bf16 (pure bandwidth)
// ---------------------------------------------------------------------------
__global__ __launch_bounds__(256) void convx_k(const float* __restrict__ x,
                                               short* __restrict__ xb) {
  const size_t i = ((size_t)blockIdx.x * 256 + threadIdx.x) * 8;
  float4 a = *(const float4*)(x + i);
  float4 b = *(const float4*)(x + i + 4);
  u32x4 p;
  p[0] = cvtpk(a.x, a.y); p[1] = cvtpk(a.z, a.w);
  p[2] = cvtpk(b.x, b.y); p[3] = cvtpk(b.z, b.w);
  *(u32x4*)(xb + i) = p;
}

// ---------------------------------------------------------------------------
// Convert + transpose: W[K][N] f32 -> Wt[N][K] bf16. 64x64 tiles.
// ---------------------------------------------------------------------------
__global__ __launch_bounds__(256, 2) void convT_k(const float* __restrict__ W,
                                                  short* __restrict__ Wt, int K, int N) {
  __shared__ short T[64][72];
  const int t = threadIdx.x;
  const int n0 = blockIdx.x * 64, k0 = blockIdx.y * 64;
  const int kr = t >> 2, c0 = (t & 3) * 16;
  const float* src = W + (size_t)(k0 + kr) * N + n0 + c0;
  float4 v0 = *(const float4*)(src + 0);
  float4 v1 = *(const float4*)(src + 4);
  float4 v2 = *(const float4*)(src + 8);
  float4 v3 = *(const float4*)(src + 12);
  T[c0 + 0][kr] = f2bf(v0.x);  T[c0 + 1][kr] = f2bf(v0.y);
  T[c0 + 2][kr] = f2bf(v0.z);  T[c0 + 3][kr] = f2bf(v0.w);
  T[c0 + 4][kr] = f2bf(v1.x);  T[c0 + 5][kr] = f2bf(v1.y);
  T[c0 + 6][kr] = f2bf(v1.z);  T[c0 + 7][kr] = f2bf(v1.w);
  T[c0 + 8][kr] = f2bf(v2.x);  T[c0 + 9][kr] = f2bf(v2.y);
  T[c0 + 10][kr] = f2bf(v2.z); T[c0 + 11][kr] = f2bf(v2.w);
  T[c0 + 12][kr] = f2bf(v3.x); T[c0 + 13][kr] = f2bf(v3.y);
  T[c0 + 14][kr] = f2bf(v3.z); T[c0 + 15][kr] = f2bf(v3.w);
  __syncthreads();
  const int nr = t >> 2, kc = (t & 3) * 16;
  s16x8 a = *(const s16x8*)&T[nr][kc];
  s16x8 b = *(const s16x8*)&T[nr][kc + 8];
  short* dst = Wt + (size_t)(n0 + nr) * K + k0 + kc;
  *(s16x8*)dst = a;
  *(s16x8*)(dst + 8) = b;
}

// ---------------------------------------------------------------------------
// GEMM C[M,N] = A[M,K] @ Bt[N,K]^T + bias. 128x128 tile, BK=32, 4 waves 2x2,
// double-buffered LDS, gload_lds staging for B (and A when ABF=1).
// SCAT=1: scatter epilogue -> q / k(tile-blocked) / vt2(tile-blocked).
// ---------------------------------------------------------------------------
template <int ABF, int SCAT>
__global__ __launch_bounds__(256, 2) void gemm_k(
    const void* __restrict__ Ap, const short* __restrict__ Bt,
    const float* __restrict__ bias,
    short* __restrict__ q_ws, short* __restrict__ k_ws, short* __restrict__ vt_ws,
    float* __restrict__ out, int N, int K) {
  constexpr int LDA = ABF ? 32 : 40;
  __shared__ short As[2][128 * LDA];
  __shared__ short Bs[2][128 * 32];

  const int t = threadIdx.x, l = t & 63, w = t >> 6;
  const int wm = (w >> 1) * 64, wn = (w & 1) * 64;
  const int m0 = blockIdx.x * 128, n0 = blockIdx.y * 128;
  const int lr = l & 15, lh = l >> 4;

  f32x4 acc[4][4];
#pragma unroll
  for (int i = 0; i < 4; i++)
#pragma unroll
    for (int j = 0; j < 4; j++) acc[i][j] = (f32x4){0.f, 0.f, 0.f, 0.f};

  const int arow = t >> 1, ac0 = (t & 1) * 16;  // ABF=0 A staging map
  const int grow = l >> 2, gc0 = (l & 3) * 8;   // gload lane map: 16 rows / KB

  auto stage = [&](int b, int kt) {
    {
      const int r0 = w * 32;
      const short* s0 = Bt + (size_t)(n0 + r0 + grow) * K + kt + gc0;
      gload16(s0, &Bs[b][r0 * 32]);
      gload16(s0 + (size_t)16 * K, &Bs[b][(r0 + 16) * 32]);
    }
    if constexpr (ABF) {
      const int r0 = w * 32;
      const short* s0 = (const short*)Ap + (size_t)(m0 + r0 + grow) * K + kt + gc0;
      gload16(s0, &As[b][r0 * 32]);
      gload16(s0 + (size_t)16 * K, &As[b][(r0 + 16) * 32]);
    } else {
      const float* ap = (const float*)Ap + (size_t)(m0 + arow) * K + kt + ac0;
      float4 v0 = *(const float4*)(ap + 0);
      float4 v1 = *(const float4*)(ap + 4);
      float4 v2 = *(const float4*)(ap + 8);
      float4 v3 = *(const float4*)(ap + 12);
      u32x4 p0, p1;
      p0[0] = cvtpk(v0.x, v0.y); p0[1] = cvtpk(v0.z, v0.w);
      p0[2] = cvtpk(v1.x, v1.y); p0[3] = cvtpk(v1.z, v1.w);
      p1[0] = cvtpk(v2.x, v2.y); p1[1] = cvtpk(v2.z, v2.w);
      p1[2] = cvtpk(v3.x, v3.y); p1[3] = cvtpk(v3.z, v3.w);
      *(u32x4*)&As[b][arow * LDA + ac0] = p0;
      *(u32x4*)&As[b][arow * LDA + ac0 + 8] = p1;
    }
  };

  const int nt = K >> 5;
  stage(0, 0);
  __syncthreads();
  int cur = 0;
  for (int tt = 0; tt < nt; tt++) {
    if (tt + 1 < nt) stage(cur ^ 1, (tt + 1) * 32);
    s16x8 af[4], bfv[4];
#pragma unroll
    for (int mi = 0; mi < 4; mi++)
      af[mi] = *(const s16x8*)&As[cur][(wm + mi * 16 + lr) * LDA + lh * 8];
#pragma unroll
    for (int ni = 0; ni < 4; ni++)
      bfv[ni] = *(const s16x8*)&Bs[cur][(wn + ni * 16 + lr) * 32 + lh * 8];
#pragma unroll
    for (int mi = 0; mi < 4; mi++)
#pragma unroll
      for (int ni = 0; ni < 4; ni++)
        acc[mi][ni] = __builtin_amdgcn_mfma_f32_16x16x32_bf16(af[mi], bfv[ni],
                                                              acc[mi][ni], 0, 0, 0);
    __syncthreads();
    cur ^= 1;
  }

#pragma unroll
  for (int mi = 0; mi < 4; mi++) {
#pragma unroll
    for (int ni = 0; ni < 4; ni++) {
      const int gn = n0 + wn + ni * 16 + lr;
      const float bb = bias[gn];
      if constexpr (SCAT) {
        const int sect = gn >> 10, dd = gn & 1023, hh = dd >> 6, hd = dd & 63;
#pragma unroll
        for (int j = 0; j < 4; j++) {
          const int gm = m0 + wm + mi * 16 + lh * 4 + j;  // token s
          const short bv = f2bf(acc[mi][ni][j] + bb);
          if (sect == 0)
            q_ws[((size_t)hh * 4096 + gm) * 64 + hd] = bv;
          else if (sect == 1)  // K tile-blocked: [h][t][kv32][hd64]
            k_ws[(((size_t)hh * 128 + (gm >> 5)) * 32 + (gm & 31)) * 64 + hd] = bv;
          else  // V^T tile-blocked: [h][t][hd64][kv32]
            vt_ws[(((size_t)hh * 128 + (gm >> 5)) * 64 + hd) * 32 + (gm & 31)] = bv;
        }
      } else {
#pragma unroll
        for (int j = 0; j < 4; j++) {
          const int gm = m0 + wm + mi * 16 + lh * 4 + j;
          out[(size_t)gm * N + gn] = acc[mi][ni][j] + bb;
        }
      }
    }
  }
}

// ---------------------------------------------------------------------------
// Flash attention v5: 32x32x16 MFMA, swapped QK^T, in-register softmax + P,
// barrier-free main loop with global->VGPR K/V fragments (K prefetch depth 1,
// V issued a softmax ahead of use). Wave = (32-row strip, kv-quarter); block =
// strip pair (p, 127-p): wave w does quarter w of strip p, then quarter 3-w of
// strip 127-p => 32 +- 1 tiles for EVERY wave (perfect balance, no tail).
// 4-way kv-partials combined per strip via small LDS reduction.
// ---------------------------------------------------------------------------
__global__ __launch_bounds__(256, 3) void attn_k(
    const short* __restrict__ q_ws, const short* __restrict__ k_ws,
    const short* __restrict__ vt2, short* __restrict__ o_ws) {
  __shared__ float accO[32][64];
  __shared__ float mls[4][2][32];
  __shared__ float lsS[32];

  const int tid = threadIdx.x, l = tid & 63, w = tid >> 6;
  const int ql = l & 31, hi = l >> 5;
  const int h = blockIdx.y;
  const int p = blockIdx.x;  // strip pair (p, 127-p)

  f32x16 po0, po1;
  float m, ls;
  s16x8 qf0, qf1, qf2, qf3;
  s16x8 kf0, kf1, kf2, kf3;

  auto phase = [&](int s, int t0, int t1) {
#pragma unroll
    for (int r = 0; r < 16; r++) { po0[r] = 0.f; po1[r] = 0.f; }
    m = -1e30f;
    ls = 0.f;
    {
      const short* qp = q_ws + ((size_t)h * 4096 + 32 * s + ql) * 64 + hi * 8;
      qf0 = *(const s16x8*)(qp);
      qf1 = *(const s16x8*)(qp + 16);
      qf2 = *(const s16x8*)(qp + 32);
      qf3 = *(const s16x8*)(qp + 48);
    }
    if (t0 < t1) {
      const short* kb = k_ws + (size_t)h * 262144 + (size_t)t0 * 2048 + ql * 64 + hi * 8;
      const short* vb = vt2 + (size_t)h * 262144 + (size_t)t0 * 2048 + ql * 32 + hi * 8;
      kf0 = *(const s16x8*)(kb);
      kf1 = *(const s16x8*)(kb + 16);
      kf2 = *(const s16x8*)(kb + 32);
      kf3 = *(const s16x8*)(kb + 48);
      kb += 2048;
      for (int tt = t0; tt < t1; tt++) {
        // V(tt): in flight across QK + softmax
        s16x8 vf0 = *(const s16x8*)(vb);
        s16x8 vf1 = *(const s16x8*)(vb + 16);
        s16x8 vf2 = *(const s16x8*)(vb + 1024);
        s16x8 vf3 = *(const s16x8*)(vb + 1040);
        vb += 2048;
        // S^T = K Q^T (col = q = ql, row = kv)
        f32x16 sa;
#pragma unroll
        for (int r = 0; r < 16; r++) sa[r] = 0.f;
        sa = MFMA32(kf0, qf0, sa);
        sa = MFMA32(kf1, qf1, sa);
        sa = MFMA32(kf2, qf2, sa);
        sa = MFMA32(kf3, qf3, sa);
        // prefetch K(tt+1) (harmless overread on the last tile)
        kf0 = *(const s16x8*)(kb);
        kf1 = *(const s16x8*)(kb + 16);
        kf2 = *(const s16x8*)(kb + 32);
        kf3 = *(const s16x8*)(kb + 48);
        kb += 2048;
        if (tt == s) {  // diagonal tile: mask kv > q
#pragma unroll
          for (int r = 0; r < 16; r++) {
            const int kvl = (r & 3) + 8 * (r >> 2) + 4 * hi;
            if (kvl > ql) sa[r] = -3e38f;
          }
        }
        // online softmax (log2 domain)
        const float x0 = fmaxf(fmaxf(sa[0], sa[1]), fmaxf(sa[2], sa[3]));
        const float x1 = fmaxf(fmaxf(sa[4], sa[5]), fmaxf(sa[6], sa[7]));
        const float x2 = fmaxf(fmaxf(sa[8], sa[9]), fmaxf(sa[10], sa[11]));
        const float x3 = fmaxf(fmaxf(sa[12], sa[13]), fmaxf(sa[14], sa[15]));
        float pm = fmaxf(fmaxf(x0, x1), fmaxf(x2, x3));
        pm = fmaxf(pm, __shfl_xor(pm, 32));
        pm *= SM_SCALE_LOG2;
        if (!__all(pm <= m + 8.0f)) {  // T13 defer-max
          const float nm = fmaxf(m, pm);
          const float corr = EXP2(m - nm);
          m = nm;
          ls *= corr;
#pragma unroll
          for (int r = 0; r < 16; r++) {
            const int qr = (r & 3) + 8 * (r >> 2) + 4 * hi;
            const float cq = __shfl(corr, qr);
            po0[r] *= cq;
            po1[r] *= cq;
          }
        }
        float e[16];
#pragma unroll
        for (int r = 0; r < 16; r++) e[r] = EXP2(__builtin_fmaf(sa[r], SM_SCALE_LOG2, -m));
        float rs = ((e[0] + e[1]) + (e[2] + e[3])) + ((e[4] + e[5]) + (e[6] + e[7])) +
                   (((e[8] + e[9]) + (e[10] + e[11])) + ((e[12] + e[13]) + (e[14] + e[15])));
        rs += __shfl_xor(rs, 32);
        ls += rs;
        // P -> bf16 A-frags fully in-register (cvt_pk + permlane32_swap)
        unsigned pk0 = cvtpk(e[0], e[1]), pk1 = cvtpk(e[2], e[3]);
        unsigned pk2 = cvtpk(e[4], e[5]), pk3 = cvtpk(e[6], e[7]);
        unsigned pk4 = cvtpk(e[8], e[9]), pk5 = cvtpk(e[10], e[11]);
        unsigned pk6 = cvtpk(e[12], e[13]), pk7 = cvtpk(e[14], e[15]);
        plswap(pk0, pk2);
        plswap(pk1, pk3);
        plswap(pk4, pk6);
        plswap(pk5, pk7);
        const u32x4 pw0 = {pk0, pk1, pk2, pk3};
        const u32x4 pw1 = {pk4, pk5, pk6, pk7};
        const s16x8 pa0 = __builtin_bit_cast(s16x8, pw0);
        const s16x8 pa1 = __builtin_bit_cast(s16x8, pw1);
        po0 = MFMA32(pa0, vf0, po0);
        po0 = MFMA32(pa1, vf1, po0);
        po1 = MFMA32(pa0, vf2, po1);
        po1 = MFMA32(pa1, vf3, po1);
      }
    }
    // ---- combine the 4 kv-partials of this strip (all waves participate) ----
    if (hi == 0) {
      mls[w][0][ql] = m;
      mls[w][1][ql] = ls;
    }
    __syncthreads();
    {
      const float ms = fmaxf(fmaxf(mls[0][0][ql], mls[1][0][ql]),
                             fmaxf(mls[2][0][ql], mls[3][0][ql]));
      const float lss = mls[0][1][ql] * EXP2(mls[0][0][ql] - ms) +
                        mls[1][1][ql] * EXP2(mls[1][0][ql] - ms) +
                        mls[2][1][ql] * EXP2(mls[2][0][ql] - ms) +
                        mls[3][1][ql] * EXP2(mls[3][0][ql] - ms);
      if (w == 0 && hi == 0) lsS[ql] = lss;
    }
#pragma unroll
    for (int r = 0; r < 16; r++) {
      const int qr = (r & 3) + 8 * (r >> 2) + 4 * hi;
      const float msq = fmaxf(fmaxf(mls[0][0][qr], mls[1][0][qr]),
                              fmaxf(mls[2][0][qr], mls[3][0][qr]));
      const float er = EXP2(mls[w][0][qr] - msq);
      po0[r] *= er;
      po1[r] *= er;
    }
#pragma unroll
    for (int wv = 0; wv < 4; wv++) {
      if (w == wv) {
#pragma unroll
        for (int r = 0; r < 16; r++) {
          const int qr = (r & 3) + 8 * (r >> 2) + 4 * hi;
          if (wv == 0) {
            accO[qr][ql] = po0[r];
            accO[qr][32 + ql] = po1[r];
          } else {
            accO[qr][ql] += po0[r];
            accO[qr][32 + ql] += po1[r];
          }
        }
      }
      __syncthreads();
    }
    {
      const int qo = tid >> 3, d0 = (tid & 7) * 8;
      const float inv = 1.0f / lsS[qo];
      s16x8 ov;
#pragma unroll
      for (int j = 0; j < 8; j++) ov[j] = f2bf(accO[qo][d0 + j] * inv);
      *(s16x8*)(o_ws + (size_t)(32 * s + qo) * 1024 + h * 64 + d0) = ov;
    }
    __syncthreads();  // LDS reused by next phase
  };

  const int ntA = p + 1, ntB = 128 - p;
  phase(p, (ntA * w) >> 2, (ntA * (w + 1)) >> 2);
  phase(127 - p, (ntB * (3 - w)) >> 2, (ntB * (4 - w)) >> 2);
}

// ---------------------------------------------------------------------------
extern "C" void kernel_launch(void* const* d_in, const int* in_sizes, int n_in,
                              void* d_out, int out_size, void* d_ws, size_t ws_size,
                              hipStream_t stream) {
  const float* x     = (const float*)d_in[0];
  const float* W_qkv = (const float*)d_in[1];
  const float* b_qkv = (const float*)d_in[2];
  const float* W_out = (const float*)d_in[3];
  const float* b_out = (const float*)d_in[4];
  float* out = (float*)d_out;

  short* R0    = (short*)d_ws;                     // Wqkv_t then O (8MB)
  short* q_ws  = R0 + (size_t)4 * 1024 * 1024;
  short* k_ws  = q_ws + (size_t)4 * 1024 * 1024;
  short* vt_ws = k_ws + (size_t)4 * 1024 * 1024;
  short* Wo_t  = vt_ws;                            // overlays V^T after attn
  short* xbf   = vt_ws + (size_t)4 * 1024 * 1024;  // optional +8MB region

  const bool big_ws = ws_size >= (size_t)40 * 1024 * 1024;

  // W_qkv [1024][3072] -> Wqkv_t [3072][1024] bf16
  convT_k<<<dim3(48, 16), 256, 0, stream>>>(W_qkv, R0, 1024, 3072);
  if (big_ws) {
    convx_k<<<2048, 256, 0, stream>>>(x, xbf);
    gemm_k<1, 1><<<dim3(32, 24), 256, 0, stream>>>(xbf, R0, b_qkv, q_ws, k_ws,
                                                   vt_ws, nullptr, 3072, 1024);
  } else {
    gemm_k<0, 1><<<dim3(32, 24), 256, 0, stream>>>(x, R0, b_qkv, q_ws, k_ws,
                                                   vt_ws, nullptr, 3072, 1024);
  }
  // causal flash attention -> O bf16 (overlays Wqkv_t)
  attn_k<<<dim3(64, 16), 256, 0, stream>>>(q_ws, k_ws, vt_ws, R0);
  // W_out -> Wo_t bf16 (overlays dead V^T)
  convT_k<<<dim3(16, 16), 256, 0, stream>>>(W_out, Wo_t, 1024, 1024);
  // O @ W_out + b_out -> f32
  gemm_k<1, 0><<<dim3(32, 8), 256, 0, stream>>>(R0, Wo_t, b_out, nullptr, nullptr,
                                                nullptr, out, 1024, 1024);
}

// Round 6
// 218.826 us; speedup vs baseline: 2.1943x; 1.1473x over previous
//
#include <hip/hip_runtime.h>
#include <cstdint>
#include <cstddef>

// Fused causal self-attention, MI355X gfx950. B=1,S=4096,D=1024,H=16,HD=64.
// ws layout (shorts), base 32MB + optional 8MB:
//   R0 @0    : Wqkv_t [3072][1024] bf16 (6MB), later overlaid by O [4096][1024] bf16 (8MB)
//   q  @4M   : Q  [16][4096][64] bf16
//   k  @8M   : K  [16][4096][64] bf16, hd-swizzled: pos = hd ^ ((s&7)<<3)
//   vt @12M  : V^T[16][64][4096] bf16, s-swizzled:  pos = s  ^ ((hd&7)<<3)
//              later overlaid by Wo_t [1024][1024] bf16 (after attn)
//   xbf @16M (elems): x as bf16 [4096][1024] -- only if ws_size >= 40MB
// attn v6: block = 4 waves (2 q-strips x 2 kv-halves) on a 64-row q-block,
// K/V LDS-shared (reuse 64), one barrier/tile, balanced pair (p, 63-p).

typedef __attribute__((ext_vector_type(4))) float f32x4;
typedef __attribute__((ext_vector_type(16))) float f32x16;
typedef __attribute__((ext_vector_type(8))) short s16x8;
typedef __attribute__((ext_vector_type(4))) unsigned u32x4;

#define SM_SCALE_LOG2 0.18033688011112042f  // (1/sqrt(64)) * log2(e)

#if __has_builtin(__builtin_amdgcn_exp2f)
#define EXP2(x) __builtin_amdgcn_exp2f(x)
#else
#define EXP2(x) exp2f(x)
#endif

static __device__ __forceinline__ short f2bf(float f) {
  unsigned u = __builtin_bit_cast(unsigned, f);
  u = (u + 0x7fffu + ((u >> 16) & 1u)) >> 16;  // RNE
  return (short)u;
}

static __device__ __forceinline__ unsigned cvtpk(float lo, float hi) {
  unsigned r;
  asm("v_cvt_pk_bf16_f32 %0, %1, %2" : "=v"(r) : "v"(lo), "v"(hi));
  return r;
}

// a' = {a.lanes0-31 || b.lanes0-31}, b' = {a.lanes32-63 || b.lanes32-63}
static __device__ __forceinline__ void plswap(unsigned& a, unsigned& b) {
#if __has_builtin(__builtin_amdgcn_permlane32_swap)
  auto r = __builtin_amdgcn_permlane32_swap((int)a, (int)b, false, false);
  unsigned tmp[2];
  __builtin_memcpy(tmp, &r, 8);
  a = tmp[0];
  b = tmp[1];
#else
  const unsigned xa = (unsigned)__shfl_xor((int)a, 32);
  const unsigned xb = (unsigned)__shfl_xor((int)b, 32);
  const bool hiL = (threadIdx.x & 32) != 0;
  const unsigned na = hiL ? xb : a;
  const unsigned nb = hiL ? b : xa;
  a = na;
  b = nb;
#endif
}

static __device__ __forceinline__ void gload16(const void* g, void* l) {
  __builtin_amdgcn_global_load_lds((const __attribute__((address_space(1))) void*)g,
                                   (__attribute__((address_space(3))) void*)l, 16, 0, 0);
}

#define MFMA32(A, B, C) __builtin_amdgcn_mfma_f32_32x32x16_bf16(A, B, C, 0, 0, 0)

// ---------------------------------------------------------------------------
// x [M][K] f32 -> bf16 (pure bandwidth)
// ---------------------------------------------------------------------------
__global__ __launch_bounds__(256) void convx_k(const float* __restrict__ x,
                                               short* __restrict__ xb) {
  const size_t i = ((size_t)blockIdx.x * 256 + threadIdx.x) * 8;
  float4 a = *(const float4*)(x + i);
  float4 b = *(const float4*)(x + i + 4);
  u32x4 p;
  p[0] = cvtpk(a.x, a.y); p[1] = cvtpk(a.z, a.w);
  p[2] = cvtpk(b.x, b.y); p[3] = cvtpk(b.z, b.w);
  *(u32x4*)(xb + i) = p;
}

// ---------------------------------------------------------------------------
// Convert + transpose: W[K][N] f32 -> Wt[N][K] bf16. 64x64 tiles.
// ---------------------------------------------------------------------------
__global__ __launch_bounds__(256, 2) void convT_k(const float* __restrict__ W,
                                                  short* __restrict__ Wt, int K, int N) {
  __shared__ short T[64][72];
  const int t = threadIdx.x;
  const int n0 = blockIdx.x * 64, k0 = blockIdx.y * 64;
  const int kr = t >> 2, c0 = (t & 3) * 16;
  const float* src = W + (size_t)(k0 + kr) * N + n0 + c0;
  float4 v0 = *(const float4*)(src + 0);
  float4 v1 = *(const float4*)(src + 4);
  float4 v2 = *(const float4*)(src + 8);
  float4 v3 = *(const float4*)(src + 12);
  T[c0 + 0][kr] = f2bf(v0.x);  T[c0 + 1][kr] = f2bf(v0.y);
  T[c0 + 2][kr] = f2bf(v0.z);  T[c0 + 3][kr] = f2bf(v0.w);
  T[c0 + 4][kr] = f2bf(v1.x);  T[c0 + 5][kr] = f2bf(v1.y);
  T[c0 + 6][kr] = f2bf(v1.z);  T[c0 + 7][kr] = f2bf(v1.w);
  T[c0 + 8][kr] = f2bf(v2.x);  T[c0 + 9][kr] = f2bf(v2.y);
  T[c0 + 10][kr] = f2bf(v2.z); T[c0 + 11][kr] = f2bf(v2.w);
  T[c0 + 12][kr] = f2bf(v3.x); T[c0 + 13][kr] = f2bf(v3.y);
  T[c0 + 14][kr] = f2bf(v3.z); T[c0 + 15][kr] = f2bf(v3.w);
  __syncthreads();
  const int nr = t >> 2, kc = (t & 3) * 16;
  s16x8 a = *(const s16x8*)&T[nr][kc];
  s16x8 b = *(const s16x8*)&T[nr][kc + 8];
  short* dst = Wt + (size_t)(n0 + nr) * K + k0 + kc;
  *(s16x8*)dst = a;
  *(s16x8*)(dst + 8) = b;
}

// ---------------------------------------------------------------------------
// GEMM C[M,N] = A[M,K] @ Bt[N,K]^T + bias. 128x128 tile, BK=32, 4 waves 2x2,
// double-buffered LDS, gload_lds staging for B (and A when ABF=1).
// SCAT=1: scatter epilogue -> q / k(hd-swz) / vt(s-swz).
// ---------------------------------------------------------------------------
template <int ABF, int SCAT>
__global__ __launch_bounds__(256, 2) void gemm_k(
    const void* __restrict__ Ap, const short* __restrict__ Bt,
    const float* __restrict__ bias,
    short* __restrict__ q_ws, short* __restrict__ k_ws, short* __restrict__ vt_ws,
    float* __restrict__ out, int N, int K) {
  constexpr int LDA = ABF ? 32 : 40;
  __shared__ short As[2][128 * LDA];
  __shared__ short Bs[2][128 * 32];

  const int t = threadIdx.x, l = t & 63, w = t >> 6;
  const int wm = (w >> 1) * 64, wn = (w & 1) * 64;
  const int m0 = blockIdx.x * 128, n0 = blockIdx.y * 128;
  const int lr = l & 15, lh = l >> 4;

  f32x4 acc[4][4];
#pragma unroll
  for (int i = 0; i < 4; i++)
#pragma unroll
    for (int j = 0; j < 4; j++) acc[i][j] = (f32x4){0.f, 0.f, 0.f, 0.f};

  const int arow = t >> 1, ac0 = (t & 1) * 16;  // ABF=0 A staging map
  const int grow = l >> 2, gc0 = (l & 3) * 8;   // gload lane map: 16 rows / KB

  auto stage = [&](int b, int kt) {
    {
      const int r0 = w * 32;
      const short* s0 = Bt + (size_t)(n0 + r0 + grow) * K + kt + gc0;
      gload16(s0, &Bs[b][r0 * 32]);
      gload16(s0 + (size_t)16 * K, &Bs[b][(r0 + 16) * 32]);
    }
    if constexpr (ABF) {
      const int r0 = w * 32;
      const short* s0 = (const short*)Ap + (size_t)(m0 + r0 + grow) * K + kt + gc0;
      gload16(s0, &As[b][r0 * 32]);
      gload16(s0 + (size_t)16 * K, &As[b][(r0 + 16) * 32]);
    } else {
      const float* ap = (const float*)Ap + (size_t)(m0 + arow) * K + kt + ac0;
      float4 v0 = *(const float4*)(ap + 0);
      float4 v1 = *(const float4*)(ap + 4);
      float4 v2 = *(const float4*)(ap + 8);
      float4 v3 = *(const float4*)(ap + 12);
      u32x4 p0, p1;
      p0[0] = cvtpk(v0.x, v0.y); p0[1] = cvtpk(v0.z, v0.w);
      p0[2] = cvtpk(v1.x, v1.y); p0[3] = cvtpk(v1.z, v1.w);
      p1[0] = cvtpk(v2.x, v2.y); p1[1] = cvtpk(v2.z, v2.w);
      p1[2] = cvtpk(v3.x, v3.y); p1[3] = cvtpk(v3.z, v3.w);
      *(u32x4*)&As[b][arow * LDA + ac0] = p0;
      *(u32x4*)&As[b][arow * LDA + ac0 + 8] = p1;
    }
  };

  const int nt = K >> 5;
  stage(0, 0);
  __syncthreads();
  int cur = 0;
  for (int tt = 0; tt < nt; tt++) {
    if (tt + 1 < nt) stage(cur ^ 1, (tt + 1) * 32);
    s16x8 af[4], bfv[4];
#pragma unroll
    for (int mi = 0; mi < 4; mi++)
      af[mi] = *(const s16x8*)&As[cur][(wm + mi * 16 + lr) * LDA + lh * 8];
#pragma unroll
    for (int ni = 0; ni < 4; ni++)
      bfv[ni] = *(const s16x8*)&Bs[cur][(wn + ni * 16 + lr) * 32 + lh * 8];
#pragma unroll
    for (int mi = 0; mi < 4; mi++)
#pragma unroll
      for (int ni = 0; ni < 4; ni++)
        acc[mi][ni] = __builtin_amdgcn_mfma_f32_16x16x32_bf16(af[mi], bfv[ni],
                                                              acc[mi][ni], 0, 0, 0);
    __syncthreads();
    cur ^= 1;
  }

#pragma unroll
  for (int mi = 0; mi < 4; mi++) {
#pragma unroll
    for (int ni = 0; ni < 4; ni++) {
      const int gn = n0 + wn + ni * 16 + lr;
      const float bb = bias[gn];
      if constexpr (SCAT) {
        const int sect = gn >> 10, dd = gn & 1023, hh = dd >> 6, hd = dd & 63;
#pragma unroll
        for (int j = 0; j < 4; j++) {
          const int gm = m0 + wm + mi * 16 + lh * 4 + j;  // token s
          const short bv = f2bf(acc[mi][ni][j] + bb);
          if (sect == 0)
            q_ws[((size_t)hh * 4096 + gm) * 64 + hd] = bv;
          else if (sect == 1)
            k_ws[((size_t)hh * 4096 + gm) * 64 + (hd ^ ((gm & 7) << 3))] = bv;
          else
            vt_ws[((size_t)hh * 64 + hd) * 4096 + (gm ^ ((hd & 7) << 3))] = bv;
        }
      } else {
#pragma unroll
        for (int j = 0; j < 4; j++) {
          const int gm = m0 + wm + mi * 16 + lh * 4 + j;
          out[(size_t)gm * N + gn] = acc[mi][ni][j] + bb;
        }
      }
    }
  }
}

// ---------------------------------------------------------------------------
// Flash attention v6: 32x32x16 MFMA, swapped QK^T, in-register softmax + P.
// Block = 4 waves = 2 q-strips(32) x 2 kv-halves over a 64-row q-block.
// K/V (64kv x 64hd) staged once per block via global_load_lds (pre-swizzled
// sources -> linear LDS dest, XOR applied on read), double-buffered, ONE
// barrier per tile. Block handles q-blocks p and 63-p: 65 tiles for every
// block (perfect balance). 49KB LDS -> 3 blocks/CU resident.
// ---------------------------------------------------------------------------
__global__ __launch_bounds__(256, 3) void attn_k(
    const short* __restrict__ q_ws, const short* __restrict__ k_ws,
    const short* __restrict__ vt_ws, short* __restrict__ o_ws) {
  __shared__ short Ks[2][64 * 64];   // [kv][hd^((kv&7)<<3)]
  __shared__ short Vts[2][64 * 64];  // [hd][kv^((hd&7)<<3)]
  __shared__ float accO[64][64];
  __shared__ float mls[2][2][64];    // [kh][m|ls][qloc]

  const int tid = threadIdx.x, l = tid & 63, w = tid >> 6;
  const int sid = w & 1, kh = w >> 1;
  const int ql = l & 31, hi = l >> 5;
  const int lin = blockIdx.x;
  const int logical = (lin & 7) * 64 + (lin >> 3);  // bijective XCD remap (512%8==0)
  const int pair = logical & 31;
  const int h = logical >> 5;
  const int gl8 = l >> 3, gc8 = (l & 7) * 8;

  auto run = [&](int qb) {
    const int q0w = qb + 32 * sid;
    const int qg = q0w + ql;
    const int nt = (qb >> 6) + 1;

    s16x8 qf[4];
    {
      const short* qp = q_ws + ((size_t)h * 4096 + qg) * 64 + hi * 8;
      qf[0] = *(const s16x8*)qp;
      qf[1] = *(const s16x8*)(qp + 16);
      qf[2] = *(const s16x8*)(qp + 32);
      qf[3] = *(const s16x8*)(qp + 48);
    }

    f32x16 po0, po1;
#pragma unroll
    for (int r = 0; r < 16; r++) { po0[r] = 0.f; po1[r] = 0.f; }
    float m = -1e30f, ls = 0.f;

    auto stage = [&](int b, int tt) {
      const short* kb = k_ws + ((size_t)h * 4096 + (size_t)tt * 64 + w * 16 + gl8) * 64 + gc8;
      gload16(kb, &Ks[b][w * 16 * 64]);
      gload16(kb + (size_t)8 * 64, &Ks[b][(w * 16 + 8) * 64]);
      const short* vb = vt_ws + ((size_t)h * 64 + w * 16 + gl8) * 4096 + (size_t)tt * 64 + gc8;
      gload16(vb, &Vts[b][w * 16 * 64]);
      gload16(vb + (size_t)8 * 4096, &Vts[b][(w * 16 + 8) * 64]);
    };

    stage(0, 0);
    __syncthreads();
    int cur = 0;
    for (int tt = 0; tt < nt; tt++) {
      if (tt + 1 < nt) stage(cur ^ 1, tt + 1);
      const int kv0w = tt * 64 + kh * 32;
      if (kv0w <= q0w + 31) {  // wave-active
        const int row = kh * 32 + ql;
        f32x16 sa;
#pragma unroll
        for (int r = 0; r < 16; r++) sa[r] = 0.f;
#pragma unroll
        for (int ks2 = 0; ks2 < 4; ks2++) {
          s16x8 kf = *(const s16x8*)&Ks[cur][row * 64 + ((ks2 * 16 + hi * 8) ^ ((ql & 7) << 3))];
          sa = MFMA32(kf, qf[ks2], sa);
        }
        if (kv0w + 31 > q0w) {  // diagonal: mask kv > q
#pragma unroll
          for (int r = 0; r < 16; r++) {
            const int kvl = (r & 3) + 8 * (r >> 2) + 4 * hi;
            if (kv0w + kvl > qg) sa[r] = -3e38f;
          }
        }
        // online softmax (log2 domain)
        const float x0 = fmaxf(fmaxf(sa[0], sa[1]), fmaxf(sa[2], sa[3]));
        const float x1 = fmaxf(fmaxf(sa[4], sa[5]), fmaxf(sa[6], sa[7]));
        const float x2 = fmaxf(fmaxf(sa[8], sa[9]), fmaxf(sa[10], sa[11]));
        const float x3 = fmaxf(fmaxf(sa[12], sa[13]), fmaxf(sa[14], sa[15]));
        float pm = fmaxf(fmaxf(x0, x1), fmaxf(x2, x3));
        pm = fmaxf(pm, __shfl_xor(pm, 32));
        pm *= SM_SCALE_LOG2;
        if (!__all(pm <= m + 8.0f)) {  // T13 defer-max
          const float nm = fmaxf(m, pm);
          const float corr = EXP2(m - nm);
          m = nm;
          ls *= corr;
#pragma unroll
          for (int r = 0; r < 16; r++) {
            const int qr = (r & 3) + 8 * (r >> 2) + 4 * hi;
            const float cq = __shfl(corr, qr);
            po0[r] *= cq;
            po1[r] *= cq;
          }
        }
        float e[16];
#pragma unroll
        for (int r = 0; r < 16; r++) e[r] = EXP2(__builtin_fmaf(sa[r], SM_SCALE_LOG2, -m));
        float rs = ((e[0] + e[1]) + (e[2] + e[3])) + ((e[4] + e[5]) + (e[6] + e[7])) +
                   (((e[8] + e[9]) + (e[10] + e[11])) + ((e[12] + e[13]) + (e[14] + e[15])));
        rs += __shfl_xor(rs, 32);
        ls += rs;
        // P -> bf16 A-frags in-register
        unsigned pk0 = cvtpk(e[0], e[1]), pk1 = cvtpk(e[2], e[3]);
        unsigned pk2 = cvtpk(e[4], e[5]), pk3 = cvtpk(e[6], e[7]);
        unsigned pk4 = cvtpk(e[8], e[9]), pk5 = cvtpk(e[10], e[11]);
        unsigned pk6 = cvtpk(e[12], e[13]), pk7 = cvtpk(e[14], e[15]);
        plswap(pk0, pk2);
        plswap(pk1, pk3);
        plswap(pk4, pk6);
        plswap(pk5, pk7);
        const u32x4 pw0 = {pk0, pk1, pk2, pk3};
        const u32x4 pw1 = {pk4, pk5, pk6, pk7};
        const s16x8 pa0 = __builtin_bit_cast(s16x8, pw0);
        const s16x8 pa1 = __builtin_bit_cast(s16x8, pw1);
        const int kidx0 = (kh * 32 + hi * 8) ^ ((ql & 7) << 3);
        const int kidx1 = (kh * 32 + 16 + hi * 8) ^ ((ql & 7) << 3);
        s16x8 vf00 = *(const s16x8*)&Vts[cur][ql * 64 + kidx0];
        s16x8 vf01 = *(const s16x8*)&Vts[cur][ql * 64 + kidx1];
        s16x8 vf10 = *(const s16x8*)&Vts[cur][(32 + ql) * 64 + kidx0];
        s16x8 vf11 = *(const s16x8*)&Vts[cur][(32 + ql) * 64 + kidx1];
        po0 = MFMA32(pa0, vf00, po0);
        po0 = MFMA32(pa1, vf01, po0);
        po1 = MFMA32(pa0, vf10, po1);
        po1 = MFMA32(pa1, vf11, po1);
      }
      __syncthreads();
      cur ^= 1;
    }

    // ---- 2-way kv-half combine per strip ----
    const int qloc = sid * 32 + ql;
    if (hi == 0) {
      mls[kh][0][qloc] = m;
      mls[kh][1][qloc] = ls;
    }
    __syncthreads();
    float er[16];
#pragma unroll
    for (int r = 0; r < 16; r++) {
      const int qr = sid * 32 + (r & 3) + 8 * (r >> 2) + 4 * hi;
      const float mt = fmaxf(mls[0][0][qr], mls[1][0][qr]);
      er[r] = EXP2(mls[kh][0][qr] - mt);
    }
    if (kh == 0) {
#pragma unroll
      for (int r = 0; r < 16; r++) {
        const int qr = sid * 32 + (r & 3) + 8 * (r >> 2) + 4 * hi;
        accO[qr][ql] = po0[r] * er[r];
        accO[qr][32 + ql] = po1[r] * er[r];
      }
    }
    __syncthreads();
    if (kh == 1) {
#pragma unroll
      for (int r = 0; r < 16; r++) {
        const int qr = sid * 32 + (r & 3) + 8 * (r >> 2) + 4 * hi;
        accO[qr][ql] += po0[r] * er[r];
        accO[qr][32 + ql] += po1[r] * er[r];
      }
    }
    __syncthreads();
    {
      const int qo = tid >> 2, d0 = (tid & 3) * 16;
      const float m0v = mls[0][0][qo], m1v = mls[1][0][qo];
      const float mt = fmaxf(m0v, m1v);
      const float lst = mls[0][1][qo] * EXP2(m0v - mt) + mls[1][1][qo] * EXP2(m1v - mt);
      const float inv = 1.0f / lst;
      const f32x4 a0 = *(const f32x4*)&accO[qo][d0];
      const f32x4 a1 = *(const f32x4*)&accO[qo][d0 + 4];
      const f32x4 a2 = *(const f32x4*)&accO[qo][d0 + 8];
      const f32x4 a3 = *(const f32x4*)&accO[qo][d0 + 12];
      s16x8 ov0, ov1;
      ov0[0] = f2bf(a0[0] * inv); ov0[1] = f2bf(a0[1] * inv);
      ov0[2] = f2bf(a0[2] * inv); ov0[3] = f2bf(a0[3] * inv);
      ov0[4] = f2bf(a1[0] * inv); ov0[5] = f2bf(a1[1] * inv);
      ov0[6] = f2bf(a1[2] * inv); ov0[7] = f2bf(a1[3] * inv);
      ov1[0] = f2bf(a2[0] * inv); ov1[1] = f2bf(a2[1] * inv);
      ov1[2] = f2bf(a2[2] * inv); ov1[3] = f2bf(a2[3] * inv);
      ov1[4] = f2bf(a3[0] * inv); ov1[5] = f2bf(a3[1] * inv);
      ov1[6] = f2bf(a3[2] * inv); ov1[7] = f2bf(a3[3] * inv);
      short* op = o_ws + (size_t)(qb + qo) * 1024 + h * 64 + d0;
      *(s16x8*)op = ov0;
      *(s16x8*)(op + 8) = ov1;
    }
    __syncthreads();  // LDS reused by next phase
  };

  run(pair * 64);
  run((63 - pair) * 64);
}

// ---------------------------------------------------------------------------
extern "C" void kernel_launch(void* const* d_in, const int* in_sizes, int n_in,
                              void* d_out, int out_size, void* d_ws, size_t ws_size,
                              hipStream_t stream) {
  const float* x     = (const float*)d_in[0];
  const float* W_qkv = (const float*)d_in[1];
  const float* b_qkv = (const float*)d_in[2];
  const float* W_out = (const float*)d_in[3];
  const float* b_out = (const float*)d_in[4];
  float* out = (float*)d_out;

  short* R0    = (short*)d_ws;                     // Wqkv_t then O (8MB)
  short* q_ws  = R0 + (size_t)4 * 1024 * 1024;
  short* k_ws  = q_ws + (size_t)4 * 1024 * 1024;
  short* vt_ws = k_ws + (size_t)4 * 1024 * 1024;
  short* Wo_t  = vt_ws;                            // overlays V^T after attn
  short* xbf   = vt_ws + (size_t)4 * 1024 * 1024;  // optional +8MB region

  const bool big_ws = ws_size >= (size_t)40 * 1024 * 1024;

  // W_qkv [1024][3072] -> Wqkv_t [3072][1024] bf16
  convT_k<<<dim3(48, 16), 256, 0, stream>>>(W_qkv, R0, 1024, 3072);
  if (big_ws) {
    convx_k<<<2048, 256, 0, stream>>>(x, xbf);
    gemm_k<1, 1><<<dim3(32, 24), 256, 0, stream>>>(xbf, R0, b_qkv, q_ws, k_ws,
                                                   vt_ws, nullptr, 3072, 1024);
  } else {
    gemm_k<0, 1><<<dim3(32, 24), 256, 0, stream>>>(x, R0, b_qkv, q_ws, k_ws,
                                                   vt_ws, nullptr, 3072, 1024);
  }
  // causal flash attention -> O bf16 (overlays Wqkv_t)
  attn_k<<<512, 256, 0, stream>>>(q_ws, k_ws, vt_ws, R0);
  // W_out -> Wo_t bf16 (overlays dead V^T)
  convT_k<<<dim3(16, 16), 256, 0, stream>>>(W_out, Wo_t, 1024, 1024);
  // O @ W_out + b_out -> f32
  gemm_k<1, 0><<<dim3(32, 8), 256, 0, stream>>>(R0, Wo_t, b_out, nullptr, nullptr,
                                                nullptr, out, 1024, 1024);
}

// Round 8
// 212.263 us; speedup vs baseline: 2.2621x; 1.0309x over previous
//
#include <hip/hip_runtime.h>
#include <cstdint>
#include <cstddef>

// Fused causal self-attention, MI355X gfx950. B=1,S=4096,D=1024,H=16,HD=64.
// ws layout (shorts), 32MB:
//   R0 @0    : Wqkv_t [3072][1024] bf16 (6MB), later overlaid by O [4096][1024] bf16 (8MB)
//   q  @4M   : Q  [16][4096][64] bf16
//   k  @8M   : K  [16][4096][64] bf16, hd-swizzled: pos = hd ^ ((s&7)<<3)
//   vt @12M  : V^T[16][64][4096] bf16, s-swizzled:  pos = s  ^ ((hd&7)<<3)
//              later overlaid by Wo_t [1024][1024] bf16 (after attn)
//   xbf      : x as bf16 [4096][1024] lives in d_out (16MB f32 scratch, dead
//              until gemm1 overwrites it at the very end)
// attn v7: 1024 unpaired blocks (4/CU resident, 33KB LDS via accO-overlay),
// per-CU qbi sum balanced, head->XCD grouping, setprio on MFMA clusters.

typedef __attribute__((ext_vector_type(4))) float f32x4;
typedef __attribute__((ext_vector_type(16))) float f32x16;
typedef __attribute__((ext_vector_type(8))) short s16x8;
typedef __attribute__((ext_vector_type(4))) unsigned u32x4;

#define SM_SCALE_LOG2 0.18033688011112042f  // (1/sqrt(64)) * log2(e)

#if __has_builtin(__builtin_amdgcn_exp2f)
#define EXP2(x) __builtin_amdgcn_exp2f(x)
#else
#define EXP2(x) exp2f(x)
#endif

static __device__ __forceinline__ short f2bf(float f) {
  unsigned u = __builtin_bit_cast(unsigned, f);
  u = (u + 0x7fffu + ((u >> 16) & 1u)) >> 16;  // RNE
  return (short)u;
}

static __device__ __forceinline__ unsigned cvtpk(float lo, float hi) {
  unsigned r;
  asm("v_cvt_pk_bf16_f32 %0, %1, %2" : "=v"(r) : "v"(lo), "v"(hi));
  return r;
}

// a' = {a.lanes0-31 || b.lanes0-31}, b' = {a.lanes32-63 || b.lanes32-63}
static __device__ __forceinline__ void plswap(unsigned& a, unsigned& b) {
#if __has_builtin(__builtin_amdgcn_permlane32_swap)
  auto r = __builtin_amdgcn_permlane32_swap((int)a, (int)b, false, false);
  unsigned tmp[2];
  __builtin_memcpy(tmp, &r, 8);
  a = tmp[0];
  b = tmp[1];
#else
  const unsigned xa = (unsigned)__shfl_xor((int)a, 32);
  const unsigned xb = (unsigned)__shfl_xor((int)b, 32);
  const bool hiL = (threadIdx.x & 32) != 0;
  const unsigned na = hiL ? xb : a;
  const unsigned nb = hiL ? b : xa;
  a = na;
  b = nb;
#endif
}

static __device__ __forceinline__ void gload16(const void* g, void* l) {
  __builtin_amdgcn_global_load_lds((const __attribute__((address_space(1))) void*)g,
                                   (__attribute__((address_space(3))) void*)l, 16, 0, 0);
}

#define MFMA32(A, B, C) __builtin_amdgcn_mfma_f32_32x32x16_bf16(A, B, C, 0, 0, 0)

// ---------------------------------------------------------------------------
// x [M][K] f32 -> bf16 (pure bandwidth)
// ---------------------------------------------------------------------------
__global__ __launch_bounds__(256) void convx_k(const float* __restrict__ x,
                                               short* __restrict__ xb) {
  const size_t i = ((size_t)blockIdx.x * 256 + threadIdx.x) * 8;
  float4 a = *(const float4*)(x + i);
  float4 b = *(const float4*)(x + i + 4);
  u32x4 p;
  p[0] = cvtpk(a.x, a.y); p[1] = cvtpk(a.z, a.w);
  p[2] = cvtpk(b.x, b.y); p[3] = cvtpk(b.z, b.w);
  *(u32x4*)(xb + i) = p;
}

// ---------------------------------------------------------------------------
// Convert + transpose: W[K][N] f32 -> Wt[N][K] bf16. 64x64 tiles.
// ---------------------------------------------------------------------------
__global__ __launch_bounds__(256, 2) void convT_k(const float* __restrict__ W,
                                                  short* __restrict__ Wt, int K, int N) {
  __shared__ short T[64][72];
  const int t = threadIdx.x;
  const int n0 = blockIdx.x * 64, k0 = blockIdx.y * 64;
  const int kr = t >> 2, c0 = (t & 3) * 16;
  const float* src = W + (size_t)(k0 + kr) * N + n0 + c0;
  float4 v0 = *(const float4*)(src + 0);
  float4 v1 = *(const float4*)(src + 4);
  float4 v2 = *(const float4*)(src + 8);
  float4 v3 = *(const float4*)(src + 12);
  T[c0 + 0][kr] = f2bf(v0.x);  T[c0 + 1][kr] = f2bf(v0.y);
  T[c0 + 2][kr] = f2bf(v0.z);  T[c0 + 3][kr] = f2bf(v0.w);
  T[c0 + 4][kr] = f2bf(v1.x);  T[c0 + 5][kr] = f2bf(v1.y);
  T[c0 + 6][kr] = f2bf(v1.z);  T[c0 + 7][kr] = f2bf(v1.w);
  T[c0 + 8][kr] = f2bf(v2.x);  T[c0 + 9][kr] = f2bf(v2.y);
  T[c0 + 10][kr] = f2bf(v2.z); T[c0 + 11][kr] = f2bf(v2.w);
  T[c0 + 12][kr] = f2bf(v3.x); T[c0 + 13][kr] = f2bf(v3.y);
  T[c0 + 14][kr] = f2bf(v3.z); T[c0 + 15][kr] = f2bf(v3.w);
  __syncthreads();
  const int nr = t >> 2, kc = (t & 3) * 16;
  s16x8 a = *(const s16x8*)&T[nr][kc];
  s16x8 b = *(const s16x8*)&T[nr][kc + 8];
  short* dst = Wt + (size_t)(n0 + nr) * K + k0 + kc;
  *(s16x8*)dst = a;
  *(s16x8*)(dst + 8) = b;
}

// ---------------------------------------------------------------------------
// GEMM C[M,128|64] tiles = A[M,K] @ Bt[N,K]^T + bias. 128xBN tile, BK=32,
// 4 waves, double-buffered LDS, pure global_load_lds staging (A bf16).
// NI = n-frags per wave (4 -> BN=128, 2 -> BN=64).
// SCAT=1: scatter epilogue -> q / k(hd-swz) / vt(s-swz). SCAT=0: f32 out.
// ---------------------------------------------------------------------------
template <int SCAT, int NI>
__global__ __launch_bounds__(256, 2) void gemm_k(
    const short* __restrict__ Ap, const short* __restrict__ Bt,
    const float* __restrict__ bias,
    short* __restrict__ q_ws, short* __restrict__ k_ws, short* __restrict__ vt_ws,
    float* __restrict__ out, int N, int K) {
  constexpr int BN = NI * 32;
  __shared__ short As[2][128 * 32];
  __shared__ short Bs[2][BN * 32];

  const int t = threadIdx.x, l = t & 63, w = t >> 6;
  const int wm = (w >> 1) * 64, wn = (w & 1) * (NI * 16);
  const int m0 = blockIdx.x * 128, n0 = blockIdx.y * BN;
  const int lr = l & 15, lh = l >> 4;

  f32x4 acc[4][NI];
#pragma unroll
  for (int i = 0; i < 4; i++)
#pragma unroll
    for (int j = 0; j < NI; j++) acc[i][j] = (f32x4){0.f, 0.f, 0.f, 0.f};

  const int grow = l >> 2, gc0 = (l & 3) * 8;  // gload lane map: 16 rows / KB

  auto stage = [&](int b, int kt) {
    if constexpr (NI == 4) {
      const int r0 = w * 32;
      const short* s0 = Bt + (size_t)(n0 + r0 + grow) * K + kt + gc0;
      gload16(s0, &Bs[b][r0 * 32]);
      gload16(s0 + (size_t)16 * K, &Bs[b][(r0 + 16) * 32]);
    } else {
      const int r0 = w * 16;
      const short* s0 = Bt + (size_t)(n0 + r0 + grow) * K + kt + gc0;
      gload16(s0, &Bs[b][r0 * 32]);
    }
    {
      const int r0 = w * 32;
      const short* s0 = Ap + (size_t)(m0 + r0 + grow) * K + kt + gc0;
      gload16(s0, &As[b][r0 * 32]);
      gload16(s0 + (size_t)16 * K, &As[b][(r0 + 16) * 32]);
    }
  };

  const int nt = K >> 5;
  stage(0, 0);
  __syncthreads();
  int cur = 0;
  for (int tt = 0; tt < nt; tt++) {
    if (tt + 1 < nt) stage(cur ^ 1, (tt + 1) * 32);
    s16x8 af[4], bfv[NI];
#pragma unroll
    for (int mi = 0; mi < 4; mi++)
      af[mi] = *(const s16x8*)&As[cur][(wm + mi * 16 + lr) * 32 + lh * 8];
#pragma unroll
    for (int ni = 0; ni < NI; ni++)
      bfv[ni] = *(const s16x8*)&Bs[cur][(wn + ni * 16 + lr) * 32 + lh * 8];
#pragma unroll
    for (int mi = 0; mi < 4; mi++)
#pragma unroll
      for (int ni = 0; ni < NI; ni++)
        acc[mi][ni] = __builtin_amdgcn_mfma_f32_16x16x32_bf16(af[mi], bfv[ni],
                                                              acc[mi][ni], 0, 0, 0);
    __syncthreads();
    cur ^= 1;
  }

#pragma unroll
  for (int mi = 0; mi < 4; mi++) {
#pragma unroll
    for (int ni = 0; ni < NI; ni++) {
      const int gn = n0 + wn + ni * 16 + lr;
      const float bb = bias[gn];
      if constexpr (SCAT) {
        const int sect = gn >> 10, dd = gn & 1023, hh = dd >> 6, hd = dd & 63;
#pragma unroll
        for (int j = 0; j < 4; j++) {
          const int gm = m0 + wm + mi * 16 + lh * 4 + j;  // token s
          const short bv = f2bf(acc[mi][ni][j] + bb);
          if (sect == 0)
            q_ws[((size_t)hh * 4096 + gm) * 64 + hd] = bv;
          else if (sect == 1)
            k_ws[((size_t)hh * 4096 + gm) * 64 + (hd ^ ((gm & 7) << 3))] = bv;
          else
            vt_ws[((size_t)hh * 64 + hd) * 4096 + (gm ^ ((hd & 7) << 3))] = bv;
        }
      } else {
#pragma unroll
        for (int j = 0; j < 4; j++) {
          const int gm = m0 + wm + mi * 16 + lh * 4 + j;
          out[(size_t)gm * N + gn] = acc[mi][ni][j] + bb;
        }
      }
    }
  }
}

// ---------------------------------------------------------------------------
// Flash attention v7: 32x32x16 MFMA, swapped QK^T, in-register softmax + P.
// Block = 4 waves = 2 q-strips(32) x 2 kv-halves over a 64-row q-block.
// K/V staged via global_load_lds (pre-swizzled sources), double-buffered,
// one barrier/tile. 1024 unpaired blocks, 33KB LDS (accO overlays Ks after
// the loop) -> 4 blocks/CU all-resident. Per-CU qbi sum = 126 (balanced):
// blocks {c,c+256,c+512,c+768} -> qbi {m, 63-m, m+16, 47-m}.
// ---------------------------------------------------------------------------
__global__ __launch_bounds__(256, 4) void attn_k(
    const short* __restrict__ q_ws, const short* __restrict__ k_ws,
    const short* __restrict__ vt_ws, short* __restrict__ o_ws) {
  __shared__ short Ks[2][64 * 64];   // [kv][hd^((kv&7)<<3)]
  __shared__ short Vts[2][64 * 64];  // [hd][kv^((hd&7)<<3)]
  __shared__ float mls[2][2][64];    // [kh][m|ls][qloc]
  float* accO = (float*)&Ks[0][0];   // [64][64] f32, overlays Ks post-loop

  const int tid = threadIdx.x, l = tid & 63, w = tid >> 6;
  const int sid = w & 1, kh = w >> 1;
  const int ql = l & 31, hi = l >> 5;
  const int lin = blockIdx.x;
  const int j = lin & 15;
  const int h = 2 * (j & 7) + (j >> 3);  // 2 heads per XCD slot
  const int i4 = lin >> 4;               // 0..63
  int qbi;
  switch (i4 >> 4) {                     // balanced bijection (sum/CU const)
    case 0: qbi = i4; break;
    case 1: qbi = 79 - i4; break;
    case 2: qbi = i4 - 16; break;
    default: qbi = 95 - i4; break;
  }
  const int qb = qbi * 64;
  const int q0w = qb + 32 * sid;
  const int qg = q0w + ql;  // this lane's q row; softmax owner
  const int nt = qbi + 1;
  const int gl8 = l >> 3, gc8 = (l & 7) * 8;

  s16x8 qf[4];
  {
    const short* qp = q_ws + ((size_t)h * 4096 + qg) * 64 + hi * 8;
    qf[0] = *(const s16x8*)qp;
    qf[1] = *(const s16x8*)(qp + 16);
    qf[2] = *(const s16x8*)(qp + 32);
    qf[3] = *(const s16x8*)(qp + 48);
  }

  f32x16 po0, po1;
#pragma unroll
  for (int r = 0; r < 16; r++) { po0[r] = 0.f; po1[r] = 0.f; }
  float m = -1e30f, ls = 0.f;

  auto stage = [&](int b, int tt) {
    const short* kb = k_ws + ((size_t)h * 4096 + (size_t)tt * 64 + w * 16 + gl8) * 64 + gc8;
    gload16(kb, &Ks[b][w * 16 * 64]);
    gload16(kb + (size_t)8 * 64, &Ks[b][(w * 16 + 8) * 64]);
    const short* vb = vt_ws + ((size_t)h * 64 + w * 16 + gl8) * 4096 + (size_t)tt * 64 + gc8;
    gload16(vb, &Vts[b][w * 16 * 64]);
    gload16(vb + (size_t)8 * 4096, &Vts[b][(w * 16 + 8) * 64]);
  };

  stage(0, 0);
  __syncthreads();
  int cur = 0;
  for (int tt = 0; tt < nt; tt++) {
    if (tt + 1 < nt) stage(cur ^ 1, tt + 1);
    const int kv0w = tt * 64 + kh * 32;
    if (kv0w <= q0w + 31) {  // wave-active
      const int row = kh * 32 + ql;
      f32x16 sa;
#pragma unroll
      for (int r = 0; r < 16; r++) sa[r] = 0.f;
      __builtin_amdgcn_s_setprio(1);
#pragma unroll
      for (int ks2 = 0; ks2 < 4; ks2++) {
        s16x8 kf = *(const s16x8*)&Ks[cur][row * 64 + ((ks2 * 16 + hi * 8) ^ ((ql & 7) << 3))];
        sa = MFMA32(kf, qf[ks2], sa);
      }
      __builtin_amdgcn_s_setprio(0);
      if (kv0w + 31 > q0w) {  // diagonal: mask kv > q
#pragma unroll
        for (int r = 0; r < 16; r++) {
          const int kvl = (r & 3) + 8 * (r >> 2) + 4 * hi;
          if (kv0w + kvl > qg) sa[r] = -3e38f;
        }
      }
      // online softmax (log2 domain)
      const float x0 = fmaxf(fmaxf(sa[0], sa[1]), fmaxf(sa[2], sa[3]));
      const float x1 = fmaxf(fmaxf(sa[4], sa[5]), fmaxf(sa[6], sa[7]));
      const float x2 = fmaxf(fmaxf(sa[8], sa[9]), fmaxf(sa[10], sa[11]));
      const float x3 = fmaxf(fmaxf(sa[12], sa[13]), fmaxf(sa[14], sa[15]));
      float pm = fmaxf(fmaxf(x0, x1), fmaxf(x2, x3));
      pm = fmaxf(pm, __shfl_xor(pm, 32));
      pm *= SM_SCALE_LOG2;
      if (!__all(pm <= m + 8.0f)) {  // T13 defer-max
        const float nm = fmaxf(m, pm);
        const float corr = EXP2(m - nm);
        m = nm;
        ls *= corr;
#pragma unroll
        for (int r = 0; r < 16; r++) {
          const int qr = (r & 3) + 8 * (r >> 2) + 4 * hi;
          const float cq = __shfl(corr, qr);
          po0[r] *= cq;
          po1[r] *= cq;
        }
      }
      float e[16];
#pragma unroll
      for (int r = 0; r < 16; r++) e[r] = EXP2(__builtin_fmaf(sa[r], SM_SCALE_LOG2, -m));
      float rs = ((e[0] + e[1]) + (e[2] + e[3])) + ((e[4] + e[5]) + (e[6] + e[7])) +
                 (((e[8] + e[9]) + (e[10] + e[11])) + ((e[12] + e[13]) + (e[14] + e[15])));
      rs += __shfl_xor(rs, 32);
      ls += rs;
      // P -> bf16 A-frags in-register
      unsigned pk0 = cvtpk(e[0], e[1]), pk1 = cvtpk(e[2], e[3]);
      unsigned pk2 = cvtpk(e[4], e[5]), pk3 = cvtpk(e[6], e[7]);
      unsigned pk4 = cvtpk(e[8], e[9]), pk5 = cvtpk(e[10], e[11]);
      unsigned pk6 = cvtpk(e[12], e[13]), pk7 = cvtpk(e[14], e[15]);
      plswap(pk0, pk2);
      plswap(pk1, pk3);
      plswap(pk4, pk6);
      plswap(pk5, pk7);
      const u32x4 pw0 = {pk0, pk1, pk2, pk3};
      const u32x4 pw1 = {pk4, pk5, pk6, pk7};
      const s16x8 pa0 = __builtin_bit_cast(s16x8, pw0);
      const s16x8 pa1 = __builtin_bit_cast(s16x8, pw1);
      const int kidx0 = (kh * 32 + hi * 8) ^ ((ql & 7) << 3);
      const int kidx1 = (kh * 32 + 16 + hi * 8) ^ ((ql & 7) << 3);
      s16x8 vf00 = *(const s16x8*)&Vts[cur][ql * 64 + kidx0];
      s16x8 vf01 = *(const s16x8*)&Vts[cur][ql * 64 + kidx1];
      s16x8 vf10 = *(const s16x8*)&Vts[cur][(32 + ql) * 64 + kidx0];
      s16x8 vf11 = *(const s16x8*)&Vts[cur][(32 + ql) * 64 + kidx1];
      __builtin_amdgcn_s_setprio(1);
      po0 = MFMA32(pa0, vf00, po0);
      po0 = MFMA32(pa1, vf01, po0);
      po1 = MFMA32(pa0, vf10, po1);
      po1 = MFMA32(pa1, vf11, po1);
      __builtin_amdgcn_s_setprio(0);
    }
    __syncthreads();
    cur ^= 1;
  }

  // ---- 2-way kv-half combine (accO overlays Ks; Ks dead after loop) ----
  const int qloc = sid * 32 + ql;
  if (hi == 0) {
    mls[kh][0][qloc] = m;
    mls[kh][1][qloc] = ls;
  }
  __syncthreads();
  float er[16];
#pragma unroll
  for (int r = 0; r < 16; r++) {
    const int qr = sid * 32 + (r & 3) + 8 * (r >> 2) + 4 * hi;
    const float mt = fmaxf(mls[0][0][qr], mls[1][0][qr]);
    er[r] = EXP2(mls[kh][0][qr] - mt);
  }
  if (kh == 0) {
#pragma unroll
    for (int r = 0; r < 16; r++) {
      const int qr = sid * 32 + (r & 3) + 8 * (r >> 2) + 4 * hi;
      accO[qr * 64 + ql] = po0[r] * er[r];
      accO[qr * 64 + 32 + ql] = po1[r] * er[r];
    }
  }
  __syncthreads();
  if (kh == 1) {
#pragma unroll
    for (int r = 0; r < 16; r++) {
      const int qr = sid * 32 + (r & 3) + 8 * (r >> 2) + 4 * hi;
      accO[qr * 64 + ql] += po0[r] * er[r];
      accO[qr * 64 + 32 + ql] += po1[r] * er[r];
    }
  }
  __syncthreads();
  {
    const int qo = tid >> 2, d0 = (tid & 3) * 16;
    const float m0v = mls[0][0][qo], m1v = mls[1][0][qo];
    const float mt = fmaxf(m0v, m1v);
    const float lst = mls[0][1][qo] * EXP2(m0v - mt) + mls[1][1][qo] * EXP2(m1v - mt);
    const float inv = 1.0f / lst;
    const f32x4 a0 = *(const f32x4*)&accO[qo * 64 + d0];
    const f32x4 a1 = *(const f32x4*)&accO[qo * 64 + d0 + 4];
    const f32x4 a2 = *(const f32x4*)&accO[qo * 64 + d0 + 8];
    const f32x4 a3 = *(const f32x4*)&accO[qo * 64 + d0 + 12];
    s16x8 ov0, ov1;
    ov0[0] = f2bf(a0[0] * inv); ov0[1] = f2bf(a0[1] * inv);
    ov0[2] = f2bf(a0[2] * inv); ov0[3] = f2bf(a0[3] * inv);
    ov0[4] = f2bf(a1[0] * inv); ov0[5] = f2bf(a1[1] * inv);
    ov0[6] = f2bf(a1[2] * inv); ov0[7] = f2bf(a1[3] * inv);
    ov1[0] = f2bf(a2[0] * inv); ov1[1] = f2bf(a2[1] * inv);
    ov1[2] = f2bf(a2[2] * inv); ov1[3] = f2bf(a2[3] * inv);
    ov1[4] = f2bf(a3[0] * inv); ov1[5] = f2bf(a3[1] * inv);
    ov1[6] = f2bf(a3[2] * inv); ov1[7] = f2bf(a3[3] * inv);
    short* op = o_ws + (size_t)(qb + qo) * 1024 + h * 64 + d0;
    *(s16x8*)op = ov0;
    *(s16x8*)(op + 8) = ov1;
  }
}

// ---------------------------------------------------------------------------
extern "C" void kernel_launch(void* const* d_in, const int* in_sizes, int n_in,
                              void* d_out, int out_size, void* d_ws, size_t ws_size,
                              hipStream_t stream) {
  const float* x     = (const float*)d_in[0];
  const float* W_qkv = (const float*)d_in[1];
  const float* b_qkv = (const float*)d_in[2];
  const float* W_out = (const float*)d_in[3];
  const float* b_out = (const float*)d_in[4];
  float* out = (float*)d_out;

  short* R0    = (short*)d_ws;                     // Wqkv_t then O (8MB)
  short* q_ws  = R0 + (size_t)4 * 1024 * 1024;
  short* k_ws  = q_ws + (size_t)4 * 1024 * 1024;
  short* vt_ws = k_ws + (size_t)4 * 1024 * 1024;
  short* Wo_t  = vt_ws;                            // overlays V^T after attn
  short* xbf   = (short*)d_out;                    // d_out as bf16-x scratch

  // x -> bf16 into d_out scratch (dead until gemm1 writes the real output)
  convx_k<<<2048, 256, 0, stream>>>(x, xbf);
  // W_qkv [1024][3072] -> Wqkv_t [3072][1024] bf16
  convT_k<<<dim3(48, 16), 256, 0, stream>>>(W_qkv, R0, 1024, 3072);
  // x @ W_qkv + b -> Q / K(swz) / V^T(swz)   (pure gload_lds staging)
  gemm_k<1, 4><<<dim3(32, 24), 256, 0, stream>>>(xbf, R0, b_qkv, q_ws, k_ws,
                                                 vt_ws, nullptr, 3072, 1024);
  // causal flash attention -> O bf16 (overlays Wqkv_t)
  attn_k<<<1024, 256, 0, stream>>>(q_ws, k_ws, vt_ws, R0);
  // W_out -> Wo_t bf16 (overlays dead V^T)
  convT_k<<<dim3(16, 16), 256, 0, stream>>>(W_out, Wo_t, 1024, 1024);
  // O @ W_out + b_out -> f32 (128x64 tiles: 512 blocks = 2/CU)
  gemm_k<0, 2><<<dim3(32, 16), 256, 0, stream>>>(R0, Wo_t, b_out, nullptr,
                                                 nullptr, nullptr, out, 1024, 1024);
}